// Round 1
// baseline (2277.777 us; speedup 1.0000x reference)
//
#include <hip/hip_runtime.h>
#include <cmath>

#define SEQ 2048
#define DM 512
#define DFF 2048
#define NH 8
#define DKH 64
#define NROWS 8192  // B*S = 4*2048

// ---------------------------------------------------------------------------
// LayerNorm: one 64-thread block per row of 512. Unbiased std (ddof=1),
// divide by (std + eps), matching the torch module faithfully.
// ---------------------------------------------------------------------------
__global__ __launch_bounds__(64) void ln_kernel(const float* __restrict__ x,
        const float* __restrict__ g, const float* __restrict__ b,
        float* __restrict__ out) {
    int row = blockIdx.x;
    int t = threadIdx.x;
    const float* xr = x + (size_t)row * DM + t * 8;
    float v[8];
    *(float4*)&v[0] = *(const float4*)(xr);
    *(float4*)&v[4] = *(const float4*)(xr + 4);
    float s = 0.f;
    #pragma unroll
    for (int j = 0; j < 8; ++j) s += v[j];
    #pragma unroll
    for (int m = 32; m > 0; m >>= 1) s += __shfl_xor(s, m);
    float mean = s * (1.0f / DM);
    float ss = 0.f;
    #pragma unroll
    for (int j = 0; j < 8; ++j) { float d = v[j] - mean; ss += d * d; }
    #pragma unroll
    for (int m = 32; m > 0; m >>= 1) ss += __shfl_xor(ss, m);
    float inv = 1.0f / (sqrtf(ss * (1.0f / (DM - 1))) + 1e-6f);
    float gv[8], bv[8];
    *(float4*)&gv[0] = *(const float4*)(g + t * 8);
    *(float4*)&gv[4] = *(const float4*)(g + t * 8 + 4);
    *(float4*)&bv[0] = *(const float4*)(b + t * 8);
    *(float4*)&bv[4] = *(const float4*)(b + t * 8 + 4);
    float o[8];
    #pragma unroll
    for (int j = 0; j < 8; ++j) o[j] = gv[j] * (v[j] - mean) * inv + bv[j];
    float* orow = out + (size_t)row * DM + t * 8;
    *(float4*)(orow) = *(float4*)&o[0];
    *(float4*)(orow + 4) = *(float4*)&o[4];
}

// ---------------------------------------------------------------------------
// FP32 tiled SGEMM: C[M,N] = A[M,K] @ B[K,N] + bias[N] (+resid) (+relu)
// 128x128 block tile, BK=8, 256 threads, 8x8 micro-tile (split halves so
// LDS b128 reads are 2-way-conflict-free i.e. free on CDNA4).
// M%128==0, N%128==0, K%8==0 assumed (true for all shapes here).
// ---------------------------------------------------------------------------
template<bool RELU, bool HASRES>
__global__ __launch_bounds__(256) void sgemm(const float* __restrict__ A,
        const float* __restrict__ B, const float* __restrict__ bias,
        const float* __restrict__ resid, float* __restrict__ C,
        int M, int N, int K) {
    const int BK = 8;
    __shared__ float As[BK][128];
    __shared__ float Bs[BK][128];
    int tid = threadIdx.x;
    int tx = tid & 15, ty = tid >> 4;
    int m0 = blockIdx.y * 128, n0 = blockIdx.x * 128;
    float acc[8][8];
    #pragma unroll
    for (int i = 0; i < 8; ++i)
        #pragma unroll
        for (int j = 0; j < 8; ++j) acc[i][j] = 0.f;

    int arow = tid >> 1, acol = (tid & 1) * 4;
    int brow = tid >> 5, bcol = (tid & 31) * 4;

    for (int k0 = 0; k0 < K; k0 += BK) {
        float4 a = *(const float4*)(A + (size_t)(m0 + arow) * K + k0 + acol);
        As[acol + 0][arow] = a.x;
        As[acol + 1][arow] = a.y;
        As[acol + 2][arow] = a.z;
        As[acol + 3][arow] = a.w;
        *(float4*)&Bs[brow][bcol] =
            *(const float4*)(B + (size_t)(k0 + brow) * N + n0 + bcol);
        __syncthreads();
        #pragma unroll
        for (int kk = 0; kk < BK; ++kk) {
            float av[8], bv[8];
            float4 t;
            t = *(float4*)&As[kk][ty * 4];      av[0]=t.x; av[1]=t.y; av[2]=t.z; av[3]=t.w;
            t = *(float4*)&As[kk][64 + ty * 4]; av[4]=t.x; av[5]=t.y; av[6]=t.z; av[7]=t.w;
            t = *(float4*)&Bs[kk][tx * 4];      bv[0]=t.x; bv[1]=t.y; bv[2]=t.z; bv[3]=t.w;
            t = *(float4*)&Bs[kk][64 + tx * 4]; bv[4]=t.x; bv[5]=t.y; bv[6]=t.z; bv[7]=t.w;
            #pragma unroll
            for (int i = 0; i < 8; ++i)
                #pragma unroll
                for (int j = 0; j < 8; ++j) acc[i][j] += av[i] * bv[j];
        }
        __syncthreads();
    }
    // epilogue
    #pragma unroll
    for (int ih = 0; ih < 2; ++ih) {
        #pragma unroll
        for (int ii = 0; ii < 4; ++ii) {
            int i = ih * 4 + ii;
            int m = m0 + ih * 64 + ty * 4 + ii;
            #pragma unroll
            for (int jh = 0; jh < 2; ++jh) {
                int n = n0 + jh * 64 + tx * 4;
                float4 c;
                c.x = acc[i][jh * 4 + 0] + bias[n + 0];
                c.y = acc[i][jh * 4 + 1] + bias[n + 1];
                c.z = acc[i][jh * 4 + 2] + bias[n + 2];
                c.w = acc[i][jh * 4 + 3] + bias[n + 3];
                if (HASRES) {
                    float4 r = *(const float4*)(resid + (size_t)m * N + n);
                    c.x += r.x; c.y += r.y; c.z += r.z; c.w += r.w;
                }
                if (RELU) {
                    c.x = fmaxf(c.x, 0.f); c.y = fmaxf(c.y, 0.f);
                    c.z = fmaxf(c.z, 0.f); c.w = fmaxf(c.w, 0.f);
                }
                *(float4*)(C + (size_t)m * N + n) = c;
            }
        }
    }
}

// ---------------------------------------------------------------------------
// Fused flash-style attention, fp32, per (b,h) / 64-row q-tile.
// scores = floor((q.k)/8); mask==0 -> -1e9; online softmax; ctx = P@V.
// block = 256 threads: thread(ty 0..15, tx 0..15) owns q rows ty*4..+3 and
// (k or d) cols tx*4..+3. Row stats (m,l) replicated across the 16 tx lanes
// via __shfl_xor (lanes ty*16+tx share a wave quarter: xor masks 1,2,4,8).
// ---------------------------------------------------------------------------
__global__ __launch_bounds__(256) void attn_kernel(const float* __restrict__ Q,
        const float* __restrict__ K, const float* __restrict__ V,
        const int* __restrict__ mask, float* __restrict__ O) {
    __shared__ float Qs[64][64];
    __shared__ float Kst[64][64];  // transposed: [d][k]
    __shared__ float Vs[64][64];
    __shared__ float Ps[64][64];
    int tid = threadIdx.x;
    int tx = tid & 15, ty = tid >> 4;
    int bh = blockIdx.y;
    int q0 = blockIdx.x * 64;
    size_t base = (size_t)(bh >> 3) * SEQ * DM + (size_t)(bh & 7) * DKH;

    // load Q tile
    {
        int row = tid >> 2, c = (tid & 3) * 16;
        const float* src = Q + base + (size_t)(q0 + row) * DM + c;
        #pragma unroll
        for (int u = 0; u < 4; ++u)
            *(float4*)&Qs[row][c + u * 4] = *(const float4*)(src + u * 4);
    }

    float m_i[4], l_i[4], acc[4][4];
    #pragma unroll
    for (int i = 0; i < 4; ++i) {
        m_i[i] = -1e30f; l_i[i] = 0.f;
        #pragma unroll
        for (int j = 0; j < 4; ++j) acc[i][j] = 0.f;
    }

    for (int kt = 0; kt < SEQ / 64; ++kt) {
        __syncthreads();  // protect Kst/Vs from previous iteration's readers
        {
            int row = tid >> 2, c = (tid & 3) * 16;
            const float* ksrc = K + base + (size_t)(kt * 64 + row) * DM + c;
            #pragma unroll
            for (int u = 0; u < 4; ++u) {
                float4 kv = *(const float4*)(ksrc + u * 4);
                Kst[c + u * 4 + 0][row] = kv.x;
                Kst[c + u * 4 + 1][row] = kv.y;
                Kst[c + u * 4 + 2][row] = kv.z;
                Kst[c + u * 4 + 3][row] = kv.w;
            }
            const float* vsrc = V + base + (size_t)(kt * 64 + row) * DM + c;
            #pragma unroll
            for (int u = 0; u < 4; ++u)
                *(float4*)&Vs[row][c + u * 4] = *(const float4*)(vsrc + u * 4);
        }
        __syncthreads();

        // ---- scores: s[i][j] = Q[q0+ty*4+i] . K[kt*64+tx*4+j] ----
        float s[4][4];
        #pragma unroll
        for (int i = 0; i < 4; ++i)
            #pragma unroll
            for (int j = 0; j < 4; ++j) s[i][j] = 0.f;
        #pragma unroll
        for (int d4 = 0; d4 < 64; d4 += 4) {
            float qa[4][4], ka[4][4];
            #pragma unroll
            for (int i = 0; i < 4; ++i) {
                float4 t = *(float4*)&Qs[ty * 4 + i][d4];
                qa[i][0]=t.x; qa[i][1]=t.y; qa[i][2]=t.z; qa[i][3]=t.w;
            }
            #pragma unroll
            for (int dd = 0; dd < 4; ++dd) {
                float4 t = *(float4*)&Kst[d4 + dd][tx * 4];
                ka[dd][0]=t.x; ka[dd][1]=t.y; ka[dd][2]=t.z; ka[dd][3]=t.w;
            }
            #pragma unroll
            for (int i = 0; i < 4; ++i)
                #pragma unroll
                for (int j = 0; j < 4; ++j)
                    #pragma unroll
                    for (int dd = 0; dd < 4; ++dd)
                        s[i][j] += qa[i][dd] * ka[dd][j];
        }

        // ---- floor-div by 8, mask ----
        int kg = kt * 64 + tx * 4;
        #pragma unroll
        for (int i = 0; i < 4; ++i) {
            const int* mrow = mask + (size_t)(q0 + ty * 4 + i) * SEQ + kg;
            int4 mv = *(const int4*)mrow;
            s[i][0] = (mv.x == 0) ? -1e9f : floorf(s[i][0] * 0.125f);
            s[i][1] = (mv.y == 0) ? -1e9f : floorf(s[i][1] * 0.125f);
            s[i][2] = (mv.z == 0) ? -1e9f : floorf(s[i][2] * 0.125f);
            s[i][3] = (mv.w == 0) ? -1e9f : floorf(s[i][3] * 0.125f);
        }

        // ---- online softmax update ----
        #pragma unroll
        for (int i = 0; i < 4; ++i) {
            float rmax = fmaxf(fmaxf(s[i][0], s[i][1]), fmaxf(s[i][2], s[i][3]));
            #pragma unroll
            for (int m = 1; m < 16; m <<= 1) rmax = fmaxf(rmax, __shfl_xor(rmax, m));
            float newm = fmaxf(m_i[i], rmax);
            float scale = __expf(m_i[i] - newm);
            float psum = 0.f;
            #pragma unroll
            for (int j = 0; j < 4; ++j) {
                float p = __expf(s[i][j] - newm);
                Ps[ty * 4 + i][tx * 4 + j] = p;
                psum += p;
            }
            #pragma unroll
            for (int m = 1; m < 16; m <<= 1) psum += __shfl_xor(psum, m);
            l_i[i] = l_i[i] * scale + psum;
            m_i[i] = newm;
            #pragma unroll
            for (int j = 0; j < 4; ++j) acc[i][j] *= scale;
        }

        // ---- PV: acc[i][d] += sum_k P[q][k] * V[k][d] ----
        #pragma unroll
        for (int k4 = 0; k4 < 64; k4 += 4) {
            float pa[4][4], va[4][4];
            #pragma unroll
            for (int i = 0; i < 4; ++i) {
                float4 t = *(float4*)&Ps[ty * 4 + i][k4];
                pa[i][0]=t.x; pa[i][1]=t.y; pa[i][2]=t.z; pa[i][3]=t.w;
            }
            #pragma unroll
            for (int kk = 0; kk < 4; ++kk) {
                float4 t = *(float4*)&Vs[k4 + kk][tx * 4];
                va[kk][0]=t.x; va[kk][1]=t.y; va[kk][2]=t.z; va[kk][3]=t.w;
            }
            #pragma unroll
            for (int i = 0; i < 4; ++i)
                #pragma unroll
                for (int j = 0; j < 4; ++j)
                    #pragma unroll
                    for (int kk = 0; kk < 4; ++kk)
                        acc[i][j] += pa[i][kk] * va[kk][j];
        }
    }

    // epilogue: normalize and write ctx
    #pragma unroll
    for (int i = 0; i < 4; ++i) {
        float inv = 1.0f / l_i[i];
        float4 o;
        o.x = acc[i][0] * inv; o.y = acc[i][1] * inv;
        o.z = acc[i][2] * inv; o.w = acc[i][3] * inv;
        *(float4*)(O + base + (size_t)(q0 + ty * 4 + i) * DM + tx * 4) = o;
    }
}

// ---------------------------------------------------------------------------
extern "C" void kernel_launch(void* const* d_in, const int* in_sizes, int n_in,
                              void* d_out, int out_size, void* d_ws, size_t ws_size,
                              hipStream_t stream) {
    const float* x    = (const float*)d_in[0];
    const int*   mask = (const int*)d_in[1];
    const float* wq = (const float*)d_in[2];
    const float* bq = (const float*)d_in[3];
    const float* wk = (const float*)d_in[4];
    const float* bk = (const float*)d_in[5];
    const float* wv = (const float*)d_in[6];
    const float* bv = (const float*)d_in[7];
    const float* wo = (const float*)d_in[8];
    const float* bo = (const float*)d_in[9];
    const float* w1 = (const float*)d_in[10];
    const float* b1 = (const float*)d_in[11];
    const float* w2 = (const float*)d_in[12];
    const float* b2 = (const float*)d_in[13];
    const float* g1  = (const float*)d_in[14];
    const float* be1 = (const float*)d_in[15];
    const float* g2  = (const float*)d_in[16];
    const float* be2 = (const float*)d_in[17];
    float* out = (float*)d_out;

    float* ws = (float*)d_ws;
    const size_t MB4 = (size_t)4 * 1024 * 1024;  // 4Mi floats = one [8192,512]
    float* xn  = ws;            // [8192,512]
    float* q   = ws + MB4;      // [8192,512]
    float* k   = ws + 2 * MB4;  // [8192,512]
    float* v   = ws + 3 * MB4;  // [8192,512]
    float* ctx = xn;            // reuse (xn dead after QKV gemms)
    float* xn2 = q;             // reuse (q dead after attention)
    float* ff1 = ws + 2 * MB4;  // [8192,2048] overlays k,v (dead) + 8Mi fresh

    dim3 blk256(256);
    // LN1
    ln_kernel<<<NROWS, 64, 0, stream>>>(x, g1, be1, xn);
    // Q,K,V projections
    {
        dim3 grid(DM / 128, NROWS / 128);
        sgemm<false,false><<<grid, blk256, 0, stream>>>(xn, wq, bq, nullptr, q, NROWS, DM, DM);
        sgemm<false,false><<<grid, blk256, 0, stream>>>(xn, wk, bk, nullptr, k, NROWS, DM, DM);
        sgemm<false,false><<<grid, blk256, 0, stream>>>(xn, wv, bv, nullptr, v, NROWS, DM, DM);
    }
    // fused attention
    {
        dim3 grid(SEQ / 64, 4 * NH);
        attn_kernel<<<grid, blk256, 0, stream>>>(q, k, v, mask, ctx);
    }
    // out projection + residual -> d_out
    {
        dim3 grid(DM / 128, NROWS / 128);
        sgemm<false,true><<<grid, blk256, 0, stream>>>(ctx, wo, bo, x, out, NROWS, DM, DM);
    }
    // LN2
    ln_kernel<<<NROWS, 64, 0, stream>>>(out, g2, be2, xn2);
    // FF1 (+ReLU)
    {
        dim3 grid(DFF / 128, NROWS / 128);
        sgemm<true,false><<<grid, blk256, 0, stream>>>(xn2, w1, b1, nullptr, ff1, NROWS, DFF, DM);
    }
    // FF2 (+residual into d_out)
    {
        dim3 grid(DM / 128, NROWS / 128);
        sgemm<false,true><<<grid, blk256, 0, stream>>>(ff1, w2, b2, out, out, NROWS, DM, DFF);
    }
}

// Round 2
// 997.361 us; speedup vs baseline: 2.2838x; 2.2838x over previous
//
#include <hip/hip_runtime.h>
#include <cmath>

#define SEQ 2048
#define DM 512
#define DFF 2048
#define NH 8
#define DKH 64
#define NROWS 8192  // B*S = 4*2048

typedef __attribute__((ext_vector_type(8))) short bf16x8;
typedef __attribute__((ext_vector_type(16))) float f32x16;

__device__ __forceinline__ ushort f2bf(float f) {
    uint u = __float_as_uint(f);
    u += 0x7fff + ((u >> 16) & 1);
    return (ushort)(u >> 16);
}
__device__ __forceinline__ float bf2f(ushort h) {
    return __uint_as_float(((uint)h) << 16);
}
// swizzled LDS address: row-major, 64 bf16 (128B) per row, XOR bank swizzle
__device__ __forceinline__ void* swz(char* base, int row, int col) {
    int byte = (row << 7) + (col << 1);
    byte ^= (row & 7) << 4;
    return base + byte;
}

// ---------------------------------------------------------------------------
// LayerNorm (unchanged): unbiased std (ddof=1), divide by (std + eps).
// ---------------------------------------------------------------------------
__global__ __launch_bounds__(64) void ln_kernel(const float* __restrict__ x,
        const float* __restrict__ g, const float* __restrict__ b,
        float* __restrict__ out) {
    int row = blockIdx.x;
    int t = threadIdx.x;
    const float* xr = x + (size_t)row * DM + t * 8;
    float v[8];
    *(float4*)&v[0] = *(const float4*)(xr);
    *(float4*)&v[4] = *(const float4*)(xr + 4);
    float s = 0.f;
    #pragma unroll
    for (int j = 0; j < 8; ++j) s += v[j];
    #pragma unroll
    for (int m = 32; m > 0; m >>= 1) s += __shfl_xor(s, m);
    float mean = s * (1.0f / DM);
    float ss = 0.f;
    #pragma unroll
    for (int j = 0; j < 8; ++j) { float d = v[j] - mean; ss += d * d; }
    #pragma unroll
    for (int m = 32; m > 0; m >>= 1) ss += __shfl_xor(ss, m);
    float inv = 1.0f / (sqrtf(ss * (1.0f / (DM - 1))) + 1e-6f);
    float gv[8], bv[8];
    *(float4*)&gv[0] = *(const float4*)(g + t * 8);
    *(float4*)&gv[4] = *(const float4*)(g + t * 8 + 4);
    *(float4*)&bv[0] = *(const float4*)(b + t * 8);
    *(float4*)&bv[4] = *(const float4*)(b + t * 8 + 4);
    float o[8];
    #pragma unroll
    for (int j = 0; j < 8; ++j) o[j] = gv[j] * (v[j] - mean) * inv + bv[j];
    float* orow = out + (size_t)row * DM + t * 8;
    *(float4*)(orow) = *(float4*)&o[0];
    *(float4*)(orow + 4) = *(float4*)&o[4];
}

// ---------------------------------------------------------------------------
// FP32 tiled SGEMM (unchanged this round).
// ---------------------------------------------------------------------------
template<bool RELU, bool HASRES>
__global__ __launch_bounds__(256) void sgemm(const float* __restrict__ A,
        const float* __restrict__ B, const float* __restrict__ bias,
        const float* __restrict__ resid, float* __restrict__ C,
        int M, int N, int K) {
    const int BK = 8;
    __shared__ float As[BK][128];
    __shared__ float Bs[BK][128];
    int tid = threadIdx.x;
    int tx = tid & 15, ty = tid >> 4;
    int m0 = blockIdx.y * 128, n0 = blockIdx.x * 128;
    float acc[8][8];
    #pragma unroll
    for (int i = 0; i < 8; ++i)
        #pragma unroll
        for (int j = 0; j < 8; ++j) acc[i][j] = 0.f;

    int arow = tid >> 1, acol = (tid & 1) * 4;
    int brow = tid >> 5, bcol = (tid & 31) * 4;

    for (int k0 = 0; k0 < K; k0 += BK) {
        float4 a = *(const float4*)(A + (size_t)(m0 + arow) * K + k0 + acol);
        As[acol + 0][arow] = a.x;
        As[acol + 1][arow] = a.y;
        As[acol + 2][arow] = a.z;
        As[acol + 3][arow] = a.w;
        *(float4*)&Bs[brow][bcol] =
            *(const float4*)(B + (size_t)(k0 + brow) * N + n0 + bcol);
        __syncthreads();
        #pragma unroll
        for (int kk = 0; kk < BK; ++kk) {
            float av[8], bv[8];
            float4 t;
            t = *(float4*)&As[kk][ty * 4];      av[0]=t.x; av[1]=t.y; av[2]=t.z; av[3]=t.w;
            t = *(float4*)&As[kk][64 + ty * 4]; av[4]=t.x; av[5]=t.y; av[6]=t.z; av[7]=t.w;
            t = *(float4*)&Bs[kk][tx * 4];      bv[0]=t.x; bv[1]=t.y; bv[2]=t.z; bv[3]=t.w;
            t = *(float4*)&Bs[kk][64 + tx * 4]; bv[4]=t.x; bv[5]=t.y; bv[6]=t.z; bv[7]=t.w;
            #pragma unroll
            for (int i = 0; i < 8; ++i)
                #pragma unroll
                for (int j = 0; j < 8; ++j) acc[i][j] += av[i] * bv[j];
        }
        __syncthreads();
    }
    #pragma unroll
    for (int ih = 0; ih < 2; ++ih) {
        #pragma unroll
        for (int ii = 0; ii < 4; ++ii) {
            int i = ih * 4 + ii;
            int m = m0 + ih * 64 + ty * 4 + ii;
            #pragma unroll
            for (int jh = 0; jh < 2; ++jh) {
                int n = n0 + jh * 64 + tx * 4;
                float4 c;
                c.x = acc[i][jh * 4 + 0] + bias[n + 0];
                c.y = acc[i][jh * 4 + 1] + bias[n + 1];
                c.z = acc[i][jh * 4 + 2] + bias[n + 2];
                c.w = acc[i][jh * 4 + 3] + bias[n + 3];
                if (HASRES) {
                    float4 r = *(const float4*)(resid + (size_t)m * N + n);
                    c.x += r.x; c.y += r.y; c.z += r.z; c.w += r.w;
                }
                if (RELU) {
                    c.x = fmaxf(c.x, 0.f); c.y = fmaxf(c.y, 0.f);
                    c.z = fmaxf(c.z, 0.f); c.w = fmaxf(c.w, 0.f);
                }
                *(float4*)(C + (size_t)m * N + n) = c;
            }
        }
    }
}

// ---------------------------------------------------------------------------
// MFMA flash attention. Block = 256 thr (4 waves), QB=128 (32 q-rows/wave),
// K-tiles of 64. Swapped QK^T: S^T = mfma(K_frag, Q^T_frag) so each lane owns
// one q-row (col = lane&31); softmax reduce = local + shfl_xor(32).
// Split-bf16 (hi+lo) for Q,K gives ~fp32 scores for the floor() step.
// PV: ctx^T = mfma(V^T_frag, P_frag) with P round-tripped through per-wave
// LDS in natural [q][k] layout (fragment-friendly both sides).
// All LDS tiles XOR-swizzled: byte ^= (row&7)<<4.
// ---------------------------------------------------------------------------
__global__ __launch_bounds__(256, 2) void attn_kernel(
        const float* __restrict__ Q, const float* __restrict__ K,
        const float* __restrict__ V, const int* __restrict__ mask,
        float* __restrict__ O) {
    __shared__ __align__(16) char smem[40960];
    char* QhL = smem;            // staging phase: [128][64] bf16 hi
    char* QlL = smem + 16384;    //                [128][64] bf16 lo
    char* Kh  = smem;            // main loop: [64][64] bf16
    char* Kl  = smem + 8192;
    char* Vt  = smem + 16384;    // [64][64] bf16, V^T (row = d, col = key)
    int tid = threadIdx.x;
    int w = tid >> 6;
    int lane = tid & 63;
    int ln31 = lane & 31, hi = lane >> 5;
    int b = blockIdx.y >> 3, h = blockIdx.y & 7;
    int q0 = blockIdx.x * 128;
    size_t brow = (size_t)b * SEQ;
    int hcol = h * DKH;
    char* PqW = smem + 24576 + w * 4096;  // per-wave [32][64] bf16

    // ---- stage Q tile as bf16 hi/lo ----
    {
        int q = tid >> 1, d0 = (tid & 1) * 32;
        const float* src = Q + (brow + q0 + q) * DM + hcol + d0;
        #pragma unroll
        for (int u = 0; u < 4; ++u) {
            float4 f0 = *(const float4*)(src + u * 8);
            float4 f1 = *(const float4*)(src + u * 8 + 4);
            float vv[8] = {f0.x, f0.y, f0.z, f0.w, f1.x, f1.y, f1.z, f1.w};
            union { ushort u16[8]; float4 f4; } ph, pl;
            #pragma unroll
            for (int j = 0; j < 8; ++j) {
                ushort hb = f2bf(vv[j]);
                ph.u16[j] = hb;
                pl.u16[j] = f2bf(vv[j] - bf2f(hb));
            }
            *(float4*)swz(QhL, q, d0 + u * 8) = ph.f4;
            *(float4*)swz(QlL, q, d0 + u * 8) = pl.f4;
        }
    }
    __syncthreads();
    bf16x8 qfh[4], qfl[4];
    {
        int qr = w * 32 + ln31;
        #pragma unroll
        for (int c = 0; c < 4; ++c) {
            qfh[c] = *(bf16x8*)swz(QhL, qr, c * 16 + hi * 8);
            qfl[c] = *(bf16x8*)swz(QlL, qr, c * 16 + hi * 8);
        }
    }

    f32x16 ctx0, ctx1;
    #pragma unroll
    for (int r = 0; r < 16; ++r) { ctx0[r] = 0.f; ctx1[r] = 0.f; }
    float m_i = -1e30f, l_i = 0.f;
    int qglob = q0 + w * 32 + ln31;
    const int* mrow = mask + (size_t)qglob * SEQ;

    for (int kt = 0; kt < SEQ / 64; ++kt) {
        __syncthreads();  // previous tile fully consumed
        {
            // stage K (hi/lo): thread -> (key = tid>>2, d0 = (tid&3)*16)
            int key = tid >> 2, d0 = (tid & 3) * 16;
            const float* src = K + (brow + kt * 64 + key) * DM + hcol + d0;
            #pragma unroll
            for (int u = 0; u < 2; ++u) {
                float4 f0 = *(const float4*)(src + u * 8);
                float4 f1 = *(const float4*)(src + u * 8 + 4);
                float vv[8] = {f0.x, f0.y, f0.z, f0.w, f1.x, f1.y, f1.z, f1.w};
                union { ushort u16[8]; float4 f4; } ph, pl;
                #pragma unroll
                for (int j = 0; j < 8; ++j) {
                    ushort hb = f2bf(vv[j]);
                    ph.u16[j] = hb;
                    pl.u16[j] = f2bf(vv[j] - bf2f(hb));
                }
                *(float4*)swz(Kh, key, d0 + u * 8) = ph.f4;
                *(float4*)swz(Kl, key, d0 + u * 8) = pl.f4;
            }
            // stage V^T (bf16): thread -> (d = tid&63, keys kg..kg+15)
            int d = tid & 63, kg = (tid >> 6) * 16;
            const float* vs = V + (brow + kt * 64 + kg) * DM + hcol + d;
            #pragma unroll
            for (int i = 0; i < 8; ++i) {
                uint pr = (uint)f2bf(vs[(2 * i) * DM]) |
                          ((uint)f2bf(vs[(2 * i + 1) * DM]) << 16);
                *(uint*)swz(Vt, d, kg + 2 * i) = pr;
            }
        }
        __syncthreads();

        #pragma unroll
        for (int ksub = 0; ksub < 2; ++ksub) {
            // ---- S^T tile (32 keys x 32 q): 3-term split bf16 ----
            f32x16 s;
            #pragma unroll
            for (int r = 0; r < 16; ++r) s[r] = 0.f;
            #pragma unroll
            for (int c = 0; c < 4; ++c) {
                bf16x8 ka = *(bf16x8*)swz(Kh, ksub * 32 + ln31, c * 16 + hi * 8);
                bf16x8 kb = *(bf16x8*)swz(Kl, ksub * 32 + ln31, c * 16 + hi * 8);
                s = __builtin_amdgcn_mfma_f32_32x32x16_bf16(ka, qfh[c], s, 0, 0, 0);
                s = __builtin_amdgcn_mfma_f32_32x32x16_bf16(ka, qfl[c], s, 0, 0, 0);
                s = __builtin_amdgcn_mfma_f32_32x32x16_bf16(kb, qfh[c], s, 0, 0, 0);
            }
            // ---- floor(s/8), mask, online softmax ----
            // lane reg r holds key = ksub*32 + (r&3) + 8*(r>>2) + 4*hi, q = ln31
            float tmax = -1e30f;
            #pragma unroll
            for (int rg = 0; rg < 4; ++rg) {
                int4 mv = *(const int4*)(mrow + kt * 64 + ksub * 32 + rg * 8 + hi * 4);
                int mi[4] = {mv.x, mv.y, mv.z, mv.w};
                #pragma unroll
                for (int j = 0; j < 4; ++j) {
                    int r = rg * 4 + j;
                    float sc = (mi[j] == 0) ? -1e9f : floorf(s[r] * 0.125f);
                    s[r] = sc;
                    tmax = fmaxf(tmax, sc);
                }
            }
            tmax = fmaxf(tmax, __shfl_xor(tmax, 32));
            float newm = fmaxf(m_i, tmax);
            float scl = __expf(m_i - newm);
            m_i = newm;
            float psum = 0.f;
            #pragma unroll
            for (int r = 0; r < 16; ++r) {
                float p = __expf(s[r] - newm);
                s[r] = p;
                psum += p;
            }
            psum += __shfl_xor(psum, 32);
            l_i = l_i * scl + psum;
            #pragma unroll
            for (int r = 0; r < 16; ++r) { ctx0[r] *= scl; ctx1[r] *= scl; }
            // ---- write P (bf16) to per-wave LDS, natural [q][key] layout ----
            #pragma unroll
            for (int rg = 0; rg < 4; ++rg) {
                uint2 pk;
                pk.x = (uint)f2bf(s[rg * 4 + 0]) | ((uint)f2bf(s[rg * 4 + 1]) << 16);
                pk.y = (uint)f2bf(s[rg * 4 + 2]) | ((uint)f2bf(s[rg * 4 + 3]) << 16);
                *(uint2*)swz(PqW, ln31, ksub * 32 + rg * 8 + hi * 4) = pk;
            }
            // ---- PV: ctx^T += V^T @ P^T over this ksub's 32 keys ----
            #pragma unroll
            for (int cc = 0; cc < 2; ++cc) {
                int c = ksub * 2 + cc;
                bf16x8 pb  = *(bf16x8*)swz(PqW, ln31, c * 16 + hi * 8);
                bf16x8 va0 = *(bf16x8*)swz(Vt, ln31, c * 16 + hi * 8);
                bf16x8 va1 = *(bf16x8*)swz(Vt, 32 + ln31, c * 16 + hi * 8);
                ctx0 = __builtin_amdgcn_mfma_f32_32x32x16_bf16(va0, pb, ctx0, 0, 0, 0);
                ctx1 = __builtin_amdgcn_mfma_f32_32x32x16_bf16(va1, pb, ctx1, 0, 0, 0);
            }
        }
    }

    // epilogue: normalize, write ctx (row = q, col = h*64 + d)
    float inv = 1.0f / l_i;
    float* op = O + (brow + qglob) * DM + hcol;
    #pragma unroll
    for (int r = 0; r < 16; ++r) {
        int d = (r & 3) + 8 * (r >> 2) + 4 * hi;
        op[d] = ctx0[r] * inv;
        op[32 + d] = ctx1[r] * inv;
    }
}

// ---------------------------------------------------------------------------
extern "C" void kernel_launch(void* const* d_in, const int* in_sizes, int n_in,
                              void* d_out, int out_size, void* d_ws, size_t ws_size,
                              hipStream_t stream) {
    const float* x    = (const float*)d_in[0];
    const int*   mask = (const int*)d_in[1];
    const float* wq = (const float*)d_in[2];
    const float* bq = (const float*)d_in[3];
    const float* wk = (const float*)d_in[4];
    const float* bk = (const float*)d_in[5];
    const float* wv = (const float*)d_in[6];
    const float* bv = (const float*)d_in[7];
    const float* wo = (const float*)d_in[8];
    const float* bo = (const float*)d_in[9];
    const float* w1 = (const float*)d_in[10];
    const float* b1 = (const float*)d_in[11];
    const float* w2 = (const float*)d_in[12];
    const float* b2 = (const float*)d_in[13];
    const float* g1  = (const float*)d_in[14];
    const float* be1 = (const float*)d_in[15];
    const float* g2  = (const float*)d_in[16];
    const float* be2 = (const float*)d_in[17];
    float* out = (float*)d_out;

    float* ws = (float*)d_ws;
    const size_t MB4 = (size_t)4 * 1024 * 1024;
    float* xn  = ws;
    float* q   = ws + MB4;
    float* k   = ws + 2 * MB4;
    float* v   = ws + 3 * MB4;
    float* ctx = xn;
    float* xn2 = q;
    float* ff1 = ws + 2 * MB4;

    dim3 blk256(256);
    ln_kernel<<<NROWS, 64, 0, stream>>>(x, g1, be1, xn);
    {
        dim3 grid(DM / 128, NROWS / 128);
        sgemm<false,false><<<grid, blk256, 0, stream>>>(xn, wq, bq, nullptr, q, NROWS, DM, DM);
        sgemm<false,false><<<grid, blk256, 0, stream>>>(xn, wk, bk, nullptr, k, NROWS, DM, DM);
        sgemm<false,false><<<grid, blk256, 0, stream>>>(xn, wv, bv, nullptr, v, NROWS, DM, DM);
    }
    {
        dim3 grid(SEQ / 128, 4 * NH);
        attn_kernel<<<grid, blk256, 0, stream>>>(q, k, v, mask, ctx);
    }
    {
        dim3 grid(DM / 128, NROWS / 128);
        sgemm<false,true><<<grid, blk256, 0, stream>>>(ctx, wo, bo, x, out, NROWS, DM, DM);
    }
    ln_kernel<<<NROWS, 64, 0, stream>>>(out, g2, be2, xn2);
    {
        dim3 grid(DFF / 128, NROWS / 128);
        sgemm<true,false><<<grid, blk256, 0, stream>>>(xn2, w1, b1, nullptr, ff1, NROWS, DFF, DM);
    }
    {
        dim3 grid(DM / 128, NROWS / 128);
        sgemm<false,true><<<grid, blk256, 0, stream>>>(ff1, w2, b2, out, out, NROWS, DM, DFF);
    }
}

// Round 3
// 386.181 us; speedup vs baseline: 5.8982x; 2.5826x over previous
//
#include <hip/hip_runtime.h>
#include <cmath>

#define SEQ 2048
#define DM 512
#define DFF 2048
#define NH 8
#define DKH 64
#define NROWS 8192  // B*S = 4*2048

typedef __attribute__((ext_vector_type(8))) short bf16x8;
typedef __attribute__((ext_vector_type(16))) float f32x16;

__device__ __forceinline__ ushort f2bf(float f) {
    uint u = __float_as_uint(f);
    u += 0x7fff + ((u >> 16) & 1);
    return (ushort)(u >> 16);
}
__device__ __forceinline__ float bf2f(ushort h) {
    return __uint_as_float(((uint)h) << 16);
}
// attention-kernel swizzle (rows of 64 bf16 = 128B): byte ^= (row&7)<<4
__device__ __forceinline__ void* swz(char* base, int row, int col) {
    int byte = (row << 7) + (col << 1);
    byte ^= (row & 7) << 4;
    return base + byte;
}
// gemm LDS swizzle (rows of 64 bf16 = 128B): byte ^= ((row>>2)&7)<<4
// (read pattern: 32 consecutive rows x fixed 16B chunk -> 8 lanes/chunk, balanced;
//  write pattern: 8 rows x 8 chunks -> 8 lanes/chunk, balanced)
__device__ __forceinline__ void* swzg(char* base, int row, int k) {
    int byte = (row << 7) + (k << 1);
    byte ^= ((row >> 2) & 7) << 4;
    return base + byte;
}

// ---------------------------------------------------------------------------
// LayerNorm -> bf16 output (hi, and optionally lo for split-precision consumers)
// ---------------------------------------------------------------------------
template<bool SPLIT>
__global__ __launch_bounds__(64) void ln_kernel(const float* __restrict__ x,
        const float* __restrict__ g, const float* __restrict__ b,
        ushort* __restrict__ oh, ushort* __restrict__ ol) {
    int row = blockIdx.x;
    int t = threadIdx.x;
    const float* xr = x + (size_t)row * DM + t * 8;
    float v[8];
    *(float4*)&v[0] = *(const float4*)(xr);
    *(float4*)&v[4] = *(const float4*)(xr + 4);
    float s = 0.f;
    #pragma unroll
    for (int j = 0; j < 8; ++j) s += v[j];
    #pragma unroll
    for (int m = 32; m > 0; m >>= 1) s += __shfl_xor(s, m);
    float mean = s * (1.0f / DM);
    float ss = 0.f;
    #pragma unroll
    for (int j = 0; j < 8; ++j) { float d = v[j] - mean; ss += d * d; }
    #pragma unroll
    for (int m = 32; m > 0; m >>= 1) ss += __shfl_xor(ss, m);
    float inv = 1.0f / (sqrtf(ss * (1.0f / (DM - 1))) + 1e-6f);
    float gv[8], bv[8];
    *(float4*)&gv[0] = *(const float4*)(g + t * 8);
    *(float4*)&gv[4] = *(const float4*)(g + t * 8 + 4);
    *(float4*)&bv[0] = *(const float4*)(b + t * 8);
    *(float4*)&bv[4] = *(const float4*)(b + t * 8 + 4);
    union { ushort us[8]; float4 f4; } ph, pl;
    #pragma unroll
    for (int j = 0; j < 8; ++j) {
        float o = gv[j] * (v[j] - mean) * inv + bv[j];
        ushort hb = f2bf(o);
        ph.us[j] = hb;
        if (SPLIT) pl.us[j] = f2bf(o - bf2f(hb));
    }
    *(float4*)(oh + (size_t)row * DM + t * 8) = ph.f4;
    if (SPLIT) *(float4*)(ol + (size_t)row * DM + t * 8) = pl.f4;
}

// ---------------------------------------------------------------------------
// Weight transpose+convert: W[K][N] fp32 -> Wt[N][K] bf16 (hi, optional lo).
// 64x64 tiles via padded LDS.
// ---------------------------------------------------------------------------
template<bool SPLIT>
__global__ __launch_bounds__(256) void wconv(const float* __restrict__ W,
        ushort* __restrict__ Th, ushort* __restrict__ Tl, int K, int N) {
    __shared__ float tile[64][65];
    int k0 = blockIdx.x * 64, n0 = blockIdx.y * 64;
    int t = threadIdx.x;
    {
        int kr = t >> 2, c0 = (t & 3) * 16;
        const float* src = W + (size_t)(k0 + kr) * N + n0 + c0;
        #pragma unroll
        for (int j = 0; j < 4; ++j)
            *(float4*)&tile[kr][c0 + j * 4] = *(const float4*)(src + j * 4);
    }
    __syncthreads();
    int n = t >> 2, kc = (t & 3) * 16;
    union { ushort us[16]; float4 f4[2]; } ph, pl;
    #pragma unroll
    for (int j = 0; j < 16; ++j) {
        float v = tile[kc + j][n];
        ushort hb = f2bf(v);
        ph.us[j] = hb;
        if (SPLIT) pl.us[j] = f2bf(v - bf2f(hb));
    }
    ushort* dh = Th + (size_t)(n0 + n) * K + k0 + kc;
    *(float4*)(dh) = ph.f4[0];
    *(float4*)(dh + 8) = ph.f4[1];
    if (SPLIT) {
        ushort* dl = Tl + (size_t)(n0 + n) * K + k0 + kc;
        *(float4*)(dl) = pl.f4[0];
        *(float4*)(dl + 8) = pl.f4[1];
    }
}

// ---------------------------------------------------------------------------
// MFMA GEMM: C[M,N] = A[M,K] @ Bt[N,K]^T + bias (+resid) (+relu).
// A, Bt are bf16 (hi + optional lo). TERMS=3: AhBh + AhBl + AlBh (~fp32).
// 128x128 tile, BK=64, 4 waves each owning a 64x64 quadrant (2x2 of 32x32).
// mfma_f32_32x32x16_bf16, fragment conventions identical to attn_kernel:
// mfma(X,Y)[r][lane&31] = sum_k X[rmap(r)][k] * Y[lane&31][k],
// operand frag: lane reads row (lane&31), k-slice km*16 + (lane>>5)*8.
// ---------------------------------------------------------------------------
template<int TERMS, bool RELU, bool HASRES, bool OUTBF16>
__global__ __launch_bounds__(256) void mgemm(
        const ushort* __restrict__ Ah, const ushort* __restrict__ Al,
        const ushort* __restrict__ Bth, const ushort* __restrict__ Btl,
        const float* __restrict__ bias, const float* __restrict__ resid,
        float* __restrict__ Cf, ushort* __restrict__ Cb,
        int M, int N, int K) {
    __shared__ __align__(16) char smem[TERMS == 3 ? 65536 : 32768];
    char* As_h = smem;            // [128][64] bf16
    char* Bs_h = smem + 16384;    // [128][64] bf16
    char* As_l = smem + 32768;
    char* Bs_l = smem + 49152;
    int tid = threadIdx.x;
    int lane = tid & 63, w = tid >> 6;
    int ln31 = lane & 31, hi = lane >> 5;
    int mh = (w >> 1) * 64, nh = (w & 1) * 64;
    // XCD-bijective block swizzle (all grids have nwg % 8 == 0)
    int gx = gridDim.x;
    int nwg = gx * gridDim.y;
    int flat = blockIdx.y * gx + blockIdx.x;
    int sid = (flat & 7) * (nwg >> 3) + (flat >> 3);
    int n0 = (sid % gx) * 128;
    int m0 = (sid / gx) * 128;

    f32x16 acc[2][2];
    #pragma unroll
    for (int i = 0; i < 2; ++i)
        #pragma unroll
        for (int j = 0; j < 2; ++j)
            #pragma unroll
            for (int r = 0; r < 16; ++r) acc[i][j][r] = 0.f;

    for (int k0 = 0; k0 < K; k0 += 64) {
        #pragma unroll
        for (int u = 0; u < 4; ++u) {
            int cid = u * 256 + tid;
            int r = cid >> 3, kc = (cid & 7) * 8;
            *(float4*)swzg(As_h, r, kc) =
                *(const float4*)(Ah + (size_t)(m0 + r) * K + k0 + kc);
            *(float4*)swzg(Bs_h, r, kc) =
                *(const float4*)(Bth + (size_t)(n0 + r) * K + k0 + kc);
            if (TERMS == 3) {
                *(float4*)swzg(As_l, r, kc) =
                    *(const float4*)(Al + (size_t)(m0 + r) * K + k0 + kc);
                *(float4*)swzg(Bs_l, r, kc) =
                    *(const float4*)(Btl + (size_t)(n0 + r) * K + k0 + kc);
            }
        }
        __syncthreads();
        #pragma unroll
        for (int km = 0; km < 4; ++km) {
            int kk = km * 16 + hi * 8;
            bf16x8 ah[2], bh[2];
            ah[0] = *(bf16x8*)swzg(As_h, mh + ln31, kk);
            ah[1] = *(bf16x8*)swzg(As_h, mh + 32 + ln31, kk);
            bh[0] = *(bf16x8*)swzg(Bs_h, nh + ln31, kk);
            bh[1] = *(bf16x8*)swzg(Bs_h, nh + 32 + ln31, kk);
            if (TERMS == 3) {
                bf16x8 al[2], bl[2];
                al[0] = *(bf16x8*)swzg(As_l, mh + ln31, kk);
                al[1] = *(bf16x8*)swzg(As_l, mh + 32 + ln31, kk);
                bl[0] = *(bf16x8*)swzg(Bs_l, nh + ln31, kk);
                bl[1] = *(bf16x8*)swzg(Bs_l, nh + 32 + ln31, kk);
                #pragma unroll
                for (int mi = 0; mi < 2; ++mi)
                    #pragma unroll
                    for (int ni = 0; ni < 2; ++ni) {
                        acc[mi][ni] = __builtin_amdgcn_mfma_f32_32x32x16_bf16(
                            ah[mi], bh[ni], acc[mi][ni], 0, 0, 0);
                        acc[mi][ni] = __builtin_amdgcn_mfma_f32_32x32x16_bf16(
                            ah[mi], bl[ni], acc[mi][ni], 0, 0, 0);
                        acc[mi][ni] = __builtin_amdgcn_mfma_f32_32x32x16_bf16(
                            al[mi], bh[ni], acc[mi][ni], 0, 0, 0);
                    }
            } else {
                #pragma unroll
                for (int mi = 0; mi < 2; ++mi)
                    #pragma unroll
                    for (int ni = 0; ni < 2; ++ni)
                        acc[mi][ni] = __builtin_amdgcn_mfma_f32_32x32x16_bf16(
                            ah[mi], bh[ni], acc[mi][ni], 0, 0, 0);
            }
        }
        __syncthreads();
    }
    // epilogue
    float bv[2];
    bv[0] = bias[n0 + nh + ln31];
    bv[1] = bias[n0 + nh + 32 + ln31];
    #pragma unroll
    for (int mi = 0; mi < 2; ++mi)
        #pragma unroll
        for (int ni = 0; ni < 2; ++ni) {
            int n = n0 + nh + ni * 32 + ln31;
            #pragma unroll
            for (int r = 0; r < 16; ++r) {
                int m = m0 + mh + mi * 32 + (r & 3) + 8 * (r >> 2) + 4 * hi;
                float v = acc[mi][ni][r] + bv[ni];
                if (HASRES) v += resid[(size_t)m * N + n];
                if (RELU) v = fmaxf(v, 0.f);
                if (OUTBF16) Cb[(size_t)m * N + n] = f2bf(v);
                else Cf[(size_t)m * N + n] = v;
            }
        }
}

// ---------------------------------------------------------------------------
// MFMA flash attention (same as round 2; epilogue now emits bf16 ctx).
// ---------------------------------------------------------------------------
__global__ __launch_bounds__(256, 2) void attn_kernel(
        const float* __restrict__ Q, const float* __restrict__ K,
        const float* __restrict__ V, const int* __restrict__ mask,
        ushort* __restrict__ O) {
    __shared__ __align__(16) char smem[40960];
    char* QhL = smem;            // staging phase: [128][64] bf16 hi
    char* QlL = smem + 16384;    //                [128][64] bf16 lo
    char* Kh  = smem;            // main loop: [64][64] bf16
    char* Kl  = smem + 8192;
    char* Vt  = smem + 16384;    // [64][64] bf16, V^T (row = d, col = key)
    int tid = threadIdx.x;
    int w = tid >> 6;
    int lane = tid & 63;
    int ln31 = lane & 31, hi = lane >> 5;
    int b = blockIdx.y >> 3, h = blockIdx.y & 7;
    int q0 = blockIdx.x * 128;
    size_t brow = (size_t)b * SEQ;
    int hcol = h * DKH;
    char* PqW = smem + 24576 + w * 4096;  // per-wave [32][64] bf16

    {
        int q = tid >> 1, d0 = (tid & 1) * 32;
        const float* src = Q + (brow + q0 + q) * DM + hcol + d0;
        #pragma unroll
        for (int u = 0; u < 4; ++u) {
            float4 f0 = *(const float4*)(src + u * 8);
            float4 f1 = *(const float4*)(src + u * 8 + 4);
            float vv[8] = {f0.x, f0.y, f0.z, f0.w, f1.x, f1.y, f1.z, f1.w};
            union { ushort u16[8]; float4 f4; } ph, pl;
            #pragma unroll
            for (int j = 0; j < 8; ++j) {
                ushort hb = f2bf(vv[j]);
                ph.u16[j] = hb;
                pl.u16[j] = f2bf(vv[j] - bf2f(hb));
            }
            *(float4*)swz(QhL, q, d0 + u * 8) = ph.f4;
            *(float4*)swz(QlL, q, d0 + u * 8) = pl.f4;
        }
    }
    __syncthreads();
    bf16x8 qfh[4], qfl[4];
    {
        int qr = w * 32 + ln31;
        #pragma unroll
        for (int c = 0; c < 4; ++c) {
            qfh[c] = *(bf16x8*)swz(QhL, qr, c * 16 + hi * 8);
            qfl[c] = *(bf16x8*)swz(QlL, qr, c * 16 + hi * 8);
        }
    }

    f32x16 ctx0, ctx1;
    #pragma unroll
    for (int r = 0; r < 16; ++r) { ctx0[r] = 0.f; ctx1[r] = 0.f; }
    float m_i = -1e30f, l_i = 0.f;
    int qglob = q0 + w * 32 + ln31;
    const int* mrow = mask + (size_t)qglob * SEQ;

    for (int kt = 0; kt < SEQ / 64; ++kt) {
        __syncthreads();
        {
            int key = tid >> 2, d0 = (tid & 3) * 16;
            const float* src = K + (brow + kt * 64 + key) * DM + hcol + d0;
            #pragma unroll
            for (int u = 0; u < 2; ++u) {
                float4 f0 = *(const float4*)(src + u * 8);
                float4 f1 = *(const float4*)(src + u * 8 + 4);
                float vv[8] = {f0.x, f0.y, f0.z, f0.w, f1.x, f1.y, f1.z, f1.w};
                union { ushort u16[8]; float4 f4; } ph, pl;
                #pragma unroll
                for (int j = 0; j < 8; ++j) {
                    ushort hb = f2bf(vv[j]);
                    ph.u16[j] = hb;
                    pl.u16[j] = f2bf(vv[j] - bf2f(hb));
                }
                *(float4*)swz(Kh, key, d0 + u * 8) = ph.f4;
                *(float4*)swz(Kl, key, d0 + u * 8) = pl.f4;
            }
            int d = tid & 63, kg = (tid >> 6) * 16;
            const float* vs = V + (brow + kt * 64 + kg) * DM + hcol + d;
            #pragma unroll
            for (int i = 0; i < 8; ++i) {
                uint pr = (uint)f2bf(vs[(2 * i) * DM]) |
                          ((uint)f2bf(vs[(2 * i + 1) * DM]) << 16);
                *(uint*)swz(Vt, d, kg + 2 * i) = pr;
            }
        }
        __syncthreads();

        #pragma unroll
        for (int ksub = 0; ksub < 2; ++ksub) {
            f32x16 s;
            #pragma unroll
            for (int r = 0; r < 16; ++r) s[r] = 0.f;
            #pragma unroll
            for (int c = 0; c < 4; ++c) {
                bf16x8 ka = *(bf16x8*)swz(Kh, ksub * 32 + ln31, c * 16 + hi * 8);
                bf16x8 kb = *(bf16x8*)swz(Kl, ksub * 32 + ln31, c * 16 + hi * 8);
                s = __builtin_amdgcn_mfma_f32_32x32x16_bf16(ka, qfh[c], s, 0, 0, 0);
                s = __builtin_amdgcn_mfma_f32_32x32x16_bf16(ka, qfl[c], s, 0, 0, 0);
                s = __builtin_amdgcn_mfma_f32_32x32x16_bf16(kb, qfh[c], s, 0, 0, 0);
            }
            float tmax = -1e30f;
            #pragma unroll
            for (int rg = 0; rg < 4; ++rg) {
                int4 mv = *(const int4*)(mrow + kt * 64 + ksub * 32 + rg * 8 + hi * 4);
                int mi[4] = {mv.x, mv.y, mv.z, mv.w};
                #pragma unroll
                for (int j = 0; j < 4; ++j) {
                    int r = rg * 4 + j;
                    float sc = (mi[j] == 0) ? -1e9f : floorf(s[r] * 0.125f);
                    s[r] = sc;
                    tmax = fmaxf(tmax, sc);
                }
            }
            tmax = fmaxf(tmax, __shfl_xor(tmax, 32));
            float newm = fmaxf(m_i, tmax);
            float scl = __expf(m_i - newm);
            m_i = newm;
            float psum = 0.f;
            #pragma unroll
            for (int r = 0; r < 16; ++r) {
                float p = __expf(s[r] - newm);
                s[r] = p;
                psum += p;
            }
            psum += __shfl_xor(psum, 32);
            l_i = l_i * scl + psum;
            #pragma unroll
            for (int r = 0; r < 16; ++r) { ctx0[r] *= scl; ctx1[r] *= scl; }
            #pragma unroll
            for (int rg = 0; rg < 4; ++rg) {
                uint2 pk;
                pk.x = (uint)f2bf(s[rg * 4 + 0]) | ((uint)f2bf(s[rg * 4 + 1]) << 16);
                pk.y = (uint)f2bf(s[rg * 4 + 2]) | ((uint)f2bf(s[rg * 4 + 3]) << 16);
                *(uint2*)swz(PqW, ln31, ksub * 32 + rg * 8 + hi * 4) = pk;
            }
            #pragma unroll
            for (int cc = 0; cc < 2; ++cc) {
                int c = ksub * 2 + cc;
                bf16x8 pb  = *(bf16x8*)swz(PqW, ln31, c * 16 + hi * 8);
                bf16x8 va0 = *(bf16x8*)swz(Vt, ln31, c * 16 + hi * 8);
                bf16x8 va1 = *(bf16x8*)swz(Vt, 32 + ln31, c * 16 + hi * 8);
                ctx0 = __builtin_amdgcn_mfma_f32_32x32x16_bf16(va0, pb, ctx0, 0, 0, 0);
                ctx1 = __builtin_amdgcn_mfma_f32_32x32x16_bf16(va1, pb, ctx1, 0, 0, 0);
            }
        }
    }

    float inv = 1.0f / l_i;
    ushort* op = O + (brow + qglob) * DM + hcol;
    #pragma unroll
    for (int r = 0; r < 16; ++r) {
        int d = (r & 3) + 8 * (r >> 2) + 4 * hi;
        op[d] = f2bf(ctx0[r] * inv);
        op[32 + d] = f2bf(ctx1[r] * inv);
    }
}

// ---------------------------------------------------------------------------
extern "C" void kernel_launch(void* const* d_in, const int* in_sizes, int n_in,
                              void* d_out, int out_size, void* d_ws, size_t ws_size,
                              hipStream_t stream) {
    const float* x    = (const float*)d_in[0];
    const int*   mask = (const int*)d_in[1];
    const float* wq = (const float*)d_in[2];
    const float* bq = (const float*)d_in[3];
    const float* wk = (const float*)d_in[4];
    const float* bk = (const float*)d_in[5];
    const float* wv = (const float*)d_in[6];
    const float* bv = (const float*)d_in[7];
    const float* wo = (const float*)d_in[8];
    const float* bo = (const float*)d_in[9];
    const float* w1 = (const float*)d_in[10];
    const float* b1 = (const float*)d_in[11];
    const float* w2 = (const float*)d_in[12];
    const float* b2 = (const float*)d_in[13];
    const float* g1  = (const float*)d_in[14];
    const float* be1 = (const float*)d_in[15];
    const float* g2  = (const float*)d_in[16];
    const float* be2 = (const float*)d_in[17];
    float* out = (float*)d_out;

    char* ws = (char*)d_ws;
    const size_t MiB = 1024 * 1024;
    // activations
    ushort* xn_h = (ushort*)(ws);                 // [8192,512] bf16, 8 MiB
    ushort* xn_l = (ushort*)(ws + 8 * MiB);       // 8 MiB
    float*  q    = (float*)(ws + 16 * MiB);       // 16 MiB
    float*  k    = (float*)(ws + 32 * MiB);       // 16 MiB
    float*  v    = (float*)(ws + 48 * MiB);       // 16 MiB
    // weights (transposed, bf16)
    ushort* wqt_h = (ushort*)(ws + 64 * MiB);             // 512 KiB each
    ushort* wqt_l = (ushort*)(ws + 64 * MiB + 512 * 1024);
    ushort* wkt_h = (ushort*)(ws + 65 * MiB);
    ushort* wkt_l = (ushort*)(ws + 65 * MiB + 512 * 1024);
    ushort* wvt_h = (ushort*)(ws + 66 * MiB);
    ushort* wot_h = (ushort*)(ws + 66 * MiB + 512 * 1024);
    ushort* w1t_h = (ushort*)(ws + 67 * MiB);             // 2 MiB
    ushort* w2t_h = (ushort*)(ws + 69 * MiB);             // 2 MiB
    // overlays (regions dead by the time these are written)
    ushort* ctx  = xn_h;                          // 8 MiB, after QKV done
    ushort* xn2  = xn_l;                          // 8 MiB, after QKV done
    ushort* ff1  = (ushort*)(ws + 16 * MiB);      // 32 MiB over q,k (dead post-attn)

    dim3 blk256(256);
    // weight transpose+convert
    wconv<true ><<<dim3(8, 8),  blk256, 0, stream>>>(wq, wqt_h, wqt_l, DM, DM);
    wconv<true ><<<dim3(8, 8),  blk256, 0, stream>>>(wk, wkt_h, wkt_l, DM, DM);
    wconv<false><<<dim3(8, 8),  blk256, 0, stream>>>(wv, wvt_h, nullptr, DM, DM);
    wconv<false><<<dim3(8, 8),  blk256, 0, stream>>>(wo, wot_h, nullptr, DM, DM);
    wconv<false><<<dim3(8, 32), blk256, 0, stream>>>(w1, w1t_h, nullptr, DM, DFF);
    wconv<false><<<dim3(32, 8), blk256, 0, stream>>>(w2, w2t_h, nullptr, DFF, DM);
    // LN1 -> split bf16
    ln_kernel<true><<<NROWS, 64, 0, stream>>>(x, g1, be1, xn_h, xn_l);
    // Q,K (split, 3-term), V (1-term)
    {
        dim3 grid(DM / 128, NROWS / 128);
        mgemm<3,false,false,false><<<grid, blk256, 0, stream>>>(
            xn_h, xn_l, wqt_h, wqt_l, bq, nullptr, q, nullptr, NROWS, DM, DM);
        mgemm<3,false,false,false><<<grid, blk256, 0, stream>>>(
            xn_h, xn_l, wkt_h, wkt_l, bk, nullptr, k, nullptr, NROWS, DM, DM);
        mgemm<1,false,false,false><<<grid, blk256, 0, stream>>>(
            xn_h, nullptr, wvt_h, nullptr, bv, nullptr, v, nullptr, NROWS, DM, DM);
    }
    // fused attention -> ctx (bf16)
    {
        dim3 grid(SEQ / 128, 4 * NH);
        attn_kernel<<<grid, blk256, 0, stream>>>(q, k, v, mask, ctx);
    }
    // out projection + residual -> d_out (fp32)
    {
        dim3 grid(DM / 128, NROWS / 128);
        mgemm<1,false,true,false><<<grid, blk256, 0, stream>>>(
            ctx, nullptr, wot_h, nullptr, bo, x, out, nullptr, NROWS, DM, DM);
    }
    // LN2 -> bf16
    ln_kernel<false><<<NROWS, 64, 0, stream>>>(out, g2, be2, xn2, nullptr);
    // FF1 (+ReLU) -> bf16
    {
        dim3 grid(DFF / 128, NROWS / 128);
        mgemm<1,true,false,true><<<grid, blk256, 0, stream>>>(
            xn2, nullptr, w1t_h, nullptr, b1, nullptr, nullptr, ff1, NROWS, DFF, DM);
    }
    // FF2 (+residual) -> d_out
    {
        dim3 grid(DM / 128, NROWS / 128);
        mgemm<1,false,true,false><<<grid, blk256, 0, stream>>>(
            ff1, nullptr, w2t_h, nullptr, b2, out, out, nullptr, NROWS, DM, DFF);
    }
}

// Round 4
// 333.973 us; speedup vs baseline: 6.8202x; 1.1563x over previous
//
#include <hip/hip_runtime.h>
#include <cmath>

#define SEQ 2048
#define DM 512
#define DFF 2048
#define NH 8
#define DKH 64
#define NROWS 8192  // B*S = 4*2048

typedef __attribute__((ext_vector_type(8))) short bf16x8;
typedef __attribute__((ext_vector_type(16))) float f32x16;

__device__ __forceinline__ ushort f2bf(float f) {
    uint u = __float_as_uint(f);
    u += 0x7fff + ((u >> 16) & 1);
    return (ushort)(u >> 16);
}
__device__ __forceinline__ float bf2f(ushort h) {
    return __uint_as_float(((uint)h) << 16);
}
__device__ __forceinline__ uint cvtpk_bf16(float a, float b) {
    uint r;
    asm("v_cvt_pk_bf16_f32 %0, %1, %2" : "=v"(r) : "v"(a), "v"(b));
    return r;
}
// 128B-row LDS swizzle: byte ^= (row&7)<<4
__device__ __forceinline__ void* swz(char* base, int row, int col) {
    int byte = (row << 7) + (col << 1);
    byte ^= (row & 7) << 4;
    return base + byte;
}
// gemm LDS swizzle: byte ^= ((row>>2)&7)<<4
__device__ __forceinline__ void* swzg(char* base, int row, int k) {
    int byte = (row << 7) + (k << 1);
    byte ^= ((row >> 2) & 7) << 4;
    return base + byte;
}

// ---------------------------------------------------------------------------
// LayerNorm -> bf16 (hi, optional lo)
// ---------------------------------------------------------------------------
template<bool SPLIT>
__global__ __launch_bounds__(64) void ln_kernel(const float* __restrict__ x,
        const float* __restrict__ g, const float* __restrict__ b,
        ushort* __restrict__ oh, ushort* __restrict__ ol) {
    int row = blockIdx.x;
    int t = threadIdx.x;
    const float* xr = x + (size_t)row * DM + t * 8;
    float v[8];
    *(float4*)&v[0] = *(const float4*)(xr);
    *(float4*)&v[4] = *(const float4*)(xr + 4);
    float s = 0.f;
    #pragma unroll
    for (int j = 0; j < 8; ++j) s += v[j];
    #pragma unroll
    for (int m = 32; m > 0; m >>= 1) s += __shfl_xor(s, m);
    float mean = s * (1.0f / DM);
    float ss = 0.f;
    #pragma unroll
    for (int j = 0; j < 8; ++j) { float d = v[j] - mean; ss += d * d; }
    #pragma unroll
    for (int m = 32; m > 0; m >>= 1) ss += __shfl_xor(ss, m);
    float inv = 1.0f / (sqrtf(ss * (1.0f / (DM - 1))) + 1e-6f);
    float gv[8], bv[8];
    *(float4*)&gv[0] = *(const float4*)(g + t * 8);
    *(float4*)&gv[4] = *(const float4*)(g + t * 8 + 4);
    *(float4*)&bv[0] = *(const float4*)(b + t * 8);
    *(float4*)&bv[4] = *(const float4*)(b + t * 8 + 4);
    union { ushort us[8]; float4 f4; } ph, pl;
    #pragma unroll
    for (int j = 0; j < 8; ++j) {
        float o = gv[j] * (v[j] - mean) * inv + bv[j];
        ushort hb = f2bf(o);
        ph.us[j] = hb;
        if (SPLIT) pl.us[j] = f2bf(o - bf2f(hb));
    }
    *(float4*)(oh + (size_t)row * DM + t * 8) = ph.f4;
    if (SPLIT) *(float4*)(ol + (size_t)row * DM + t * 8) = pl.f4;
}

// ---------------------------------------------------------------------------
// Weight transpose+convert: W[K][N] fp32 -> Wt[N][K] bf16 (hi, optional lo)
// ---------------------------------------------------------------------------
template<bool SPLIT>
__global__ __launch_bounds__(256) void wconv(const float* __restrict__ W,
        ushort* __restrict__ Th, ushort* __restrict__ Tl, int K, int N) {
    __shared__ float tile[64][65];
    int k0 = blockIdx.x * 64, n0 = blockIdx.y * 64;
    int t = threadIdx.x;
    {
        int kr = t >> 2, c0 = (t & 3) * 16;
        const float* src = W + (size_t)(k0 + kr) * N + n0 + c0;
        #pragma unroll
        for (int j = 0; j < 4; ++j)
            *(float4*)&tile[kr][c0 + j * 4] = *(const float4*)(src + j * 4);
    }
    __syncthreads();
    int n = t >> 2, kc = (t & 3) * 16;
    union { ushort us[16]; float4 f4[2]; } ph, pl;
    #pragma unroll
    for (int j = 0; j < 16; ++j) {
        float v = tile[kc + j][n];
        ushort hb = f2bf(v);
        ph.us[j] = hb;
        if (SPLIT) pl.us[j] = f2bf(v - bf2f(hb));
    }
    ushort* dh = Th + (size_t)(n0 + n) * K + k0 + kc;
    *(float4*)(dh) = ph.f4[0];
    *(float4*)(dh + 8) = ph.f4[1];
    if (SPLIT) {
        ushort* dl = Tl + (size_t)(n0 + n) * K + k0 + kc;
        *(float4*)(dl) = pl.f4[0];
        *(float4*)(dl + 8) = pl.f4[1];
    }
}

// ---------------------------------------------------------------------------
// V transpose: vh[(b*SEQ+s)][DM] bf16 (head h cols) -> vt[(bh*64+d)][SEQ] bf16
// ---------------------------------------------------------------------------
__global__ __launch_bounds__(256) void vtrans(const ushort* __restrict__ vh,
        ushort* __restrict__ vt) {
    __shared__ __align__(16) char tile[8192];  // [64 seq][64 d] bf16, swizzled
    int s0 = blockIdx.x * 64;
    int bh = blockIdx.y;
    int b = bh >> 3, h = bh & 7;
    int t = threadIdx.x;
    {
        int r = t >> 2, co = (t & 3) * 16;
        const ushort* src = vh + (size_t)(b * SEQ + s0 + r) * DM + h * DKH + co;
        *(float4*)swz(tile, r, co) = *(const float4*)(src);
        *(float4*)swz(tile, r, co + 8) = *(const float4*)(src + 8);
    }
    __syncthreads();
    int d = t >> 2, j0 = (t & 3) * 16;
    union { ushort us[16]; float4 f4[2]; } o;
    #pragma unroll
    for (int j = 0; j < 16; ++j)
        o.us[j] = *(ushort*)swz(tile, j0 + j, d);
    ushort* dst = vt + ((size_t)bh * DKH + d) * SEQ + s0 + j0;
    *(float4*)(dst) = o.f4[0];
    *(float4*)(dst + 8) = o.f4[1];
}

// ---------------------------------------------------------------------------
// Mask -> additive bf16 bias {0, -1e9}
// ---------------------------------------------------------------------------
__global__ __launch_bounds__(256) void maskprep(const int* __restrict__ mask,
        ushort* __restrict__ mb) {
    int i = (blockIdx.x * 256 + threadIdx.x) * 8;
    int4 a = *(const int4*)(mask + i);
    int4 c = *(const int4*)(mask + i + 4);
    ushort neg = f2bf(-1e9f);
    union { ushort us[8]; float4 f4; } o;
    o.us[0] = a.x ? (ushort)0 : neg;
    o.us[1] = a.y ? (ushort)0 : neg;
    o.us[2] = a.z ? (ushort)0 : neg;
    o.us[3] = a.w ? (ushort)0 : neg;
    o.us[4] = c.x ? (ushort)0 : neg;
    o.us[5] = c.y ? (ushort)0 : neg;
    o.us[6] = c.z ? (ushort)0 : neg;
    o.us[7] = c.w ? (ushort)0 : neg;
    *(float4*)(mb + i) = o.f4;
}

// ---------------------------------------------------------------------------
// MFMA GEMM: C = A @ Bt^T + bias (+resid)(+relu). OUT: 0=f32, 1=bf16, 2=split
// ---------------------------------------------------------------------------
template<int TERMS, bool RELU, bool HASRES, int OUT>
__global__ __launch_bounds__(256) void mgemm(
        const ushort* __restrict__ Ah, const ushort* __restrict__ Al,
        const ushort* __restrict__ Bth, const ushort* __restrict__ Btl,
        const float* __restrict__ bias, const float* __restrict__ resid,
        float* __restrict__ Cf, ushort* __restrict__ Cbh,
        ushort* __restrict__ Cbl, int M, int N, int K) {
    __shared__ __align__(16) char smem[TERMS == 3 ? 65536 : 32768];
    char* As_h = smem;
    char* Bs_h = smem + 16384;
    char* As_l = smem + 32768;
    char* Bs_l = smem + 49152;
    int tid = threadIdx.x;
    int lane = tid & 63, w = tid >> 6;
    int ln31 = lane & 31, hi = lane >> 5;
    int mh = (w >> 1) * 64, nh = (w & 1) * 64;
    int gx = gridDim.x;
    int nwg = gx * gridDim.y;
    int flat = blockIdx.y * gx + blockIdx.x;
    int sid = (flat & 7) * (nwg >> 3) + (flat >> 3);
    int n0 = (sid % gx) * 128;
    int m0 = (sid / gx) * 128;

    f32x16 acc[2][2];
    #pragma unroll
    for (int i = 0; i < 2; ++i)
        #pragma unroll
        for (int j = 0; j < 2; ++j)
            #pragma unroll
            for (int r = 0; r < 16; ++r) acc[i][j][r] = 0.f;

    for (int k0 = 0; k0 < K; k0 += 64) {
        #pragma unroll
        for (int u = 0; u < 4; ++u) {
            int cid = u * 256 + tid;
            int r = cid >> 3, kc = (cid & 7) * 8;
            *(float4*)swzg(As_h, r, kc) =
                *(const float4*)(Ah + (size_t)(m0 + r) * K + k0 + kc);
            *(float4*)swzg(Bs_h, r, kc) =
                *(const float4*)(Bth + (size_t)(n0 + r) * K + k0 + kc);
            if (TERMS == 3) {
                *(float4*)swzg(As_l, r, kc) =
                    *(const float4*)(Al + (size_t)(m0 + r) * K + k0 + kc);
                *(float4*)swzg(Bs_l, r, kc) =
                    *(const float4*)(Btl + (size_t)(n0 + r) * K + k0 + kc);
            }
        }
        __syncthreads();
        #pragma unroll
        for (int km = 0; km < 4; ++km) {
            int kk = km * 16 + hi * 8;
            bf16x8 ah[2], bh[2];
            ah[0] = *(bf16x8*)swzg(As_h, mh + ln31, kk);
            ah[1] = *(bf16x8*)swzg(As_h, mh + 32 + ln31, kk);
            bh[0] = *(bf16x8*)swzg(Bs_h, nh + ln31, kk);
            bh[1] = *(bf16x8*)swzg(Bs_h, nh + 32 + ln31, kk);
            if (TERMS == 3) {
                bf16x8 al[2], bl[2];
                al[0] = *(bf16x8*)swzg(As_l, mh + ln31, kk);
                al[1] = *(bf16x8*)swzg(As_l, mh + 32 + ln31, kk);
                bl[0] = *(bf16x8*)swzg(Bs_l, nh + ln31, kk);
                bl[1] = *(bf16x8*)swzg(Bs_l, nh + 32 + ln31, kk);
                #pragma unroll
                for (int mi = 0; mi < 2; ++mi)
                    #pragma unroll
                    for (int ni = 0; ni < 2; ++ni) {
                        acc[mi][ni] = __builtin_amdgcn_mfma_f32_32x32x16_bf16(
                            ah[mi], bh[ni], acc[mi][ni], 0, 0, 0);
                        acc[mi][ni] = __builtin_amdgcn_mfma_f32_32x32x16_bf16(
                            ah[mi], bl[ni], acc[mi][ni], 0, 0, 0);
                        acc[mi][ni] = __builtin_amdgcn_mfma_f32_32x32x16_bf16(
                            al[mi], bh[ni], acc[mi][ni], 0, 0, 0);
                    }
            } else {
                #pragma unroll
                for (int mi = 0; mi < 2; ++mi)
                    #pragma unroll
                    for (int ni = 0; ni < 2; ++ni)
                        acc[mi][ni] = __builtin_amdgcn_mfma_f32_32x32x16_bf16(
                            ah[mi], bh[ni], acc[mi][ni], 0, 0, 0);
            }
        }
        __syncthreads();
    }
    float bv[2];
    bv[0] = bias[n0 + nh + ln31];
    bv[1] = bias[n0 + nh + 32 + ln31];
    #pragma unroll
    for (int mi = 0; mi < 2; ++mi)
        #pragma unroll
        for (int ni = 0; ni < 2; ++ni) {
            int n = n0 + nh + ni * 32 + ln31;
            #pragma unroll
            for (int r = 0; r < 16; ++r) {
                int m = m0 + mh + mi * 32 + (r & 3) + 8 * (r >> 2) + 4 * hi;
                float v = acc[mi][ni][r] + bv[ni];
                if (HASRES) v += resid[(size_t)m * N + n];
                if (RELU) v = fmaxf(v, 0.f);
                size_t idx = (size_t)m * N + n;
                if (OUT == 0) Cf[idx] = v;
                else if (OUT == 1) Cbh[idx] = f2bf(v);
                else {
                    ushort hb = f2bf(v);
                    Cbh[idx] = hb;
                    Cbl[idx] = f2bf(v - bf2f(hb));
                }
            }
        }
}

// ---------------------------------------------------------------------------
// MFMA flash attention, bf16 inputs (Q,K split hi/lo; V pre-transposed),
// mask as additive bf16 bias. XCD-colocated q-blocks per (b,h).
// ---------------------------------------------------------------------------
__global__ __launch_bounds__(256, 2) void attn_kernel(
        const ushort* __restrict__ Qh, const ushort* __restrict__ Ql,
        const ushort* __restrict__ Khg, const ushort* __restrict__ Klg,
        const ushort* __restrict__ Vtg, const ushort* __restrict__ mb,
        ushort* __restrict__ O) {
    __shared__ __align__(16) char smem[40960];
    char* QhL = smem;            // staging: [128][64]
    char* QlL = smem + 16384;
    char* KhL = smem;            // main loop: [64][64] each
    char* KlL = smem + 8192;
    char* VtL = smem + 16384;
    int tid = threadIdx.x;
    int w = tid >> 6, lane = tid & 63;
    int ln31 = lane & 31, hi = lane >> 5;
    // XCD swizzle: 512 wgs, 64/XCD -> 4 consecutive bh per XCD
    int f = blockIdx.y * gridDim.x + blockIdx.x;
    int g = (f & 7) * 64 + (f >> 3);
    int qb = g & 15, bh = g >> 4;
    int b = bh >> 3, h = bh & 7;
    int q0 = qb * 128;
    size_t brow = (size_t)b * SEQ;
    int hcol = h * DKH;
    char* PqW = smem + 24576 + w * 4096;  // per-wave [32][64]

    {
        int r = tid >> 1, co = (tid & 1) * 32;
        const ushort* s1 = Qh + (brow + q0 + r) * DM + hcol + co;
        const ushort* s2 = Ql + (brow + q0 + r) * DM + hcol + co;
        #pragma unroll
        for (int u = 0; u < 4; ++u) {
            *(float4*)swz(QhL, r, co + u * 8) = *(const float4*)(s1 + u * 8);
            *(float4*)swz(QlL, r, co + u * 8) = *(const float4*)(s2 + u * 8);
        }
    }
    __syncthreads();
    bf16x8 qfh[4], qfl[4];
    {
        int qr = w * 32 + ln31;
        #pragma unroll
        for (int c = 0; c < 4; ++c) {
            qfh[c] = *(bf16x8*)swz(QhL, qr, c * 16 + hi * 8);
            qfl[c] = *(bf16x8*)swz(QlL, qr, c * 16 + hi * 8);
        }
    }

    f32x16 ctx0, ctx1;
    #pragma unroll
    for (int r = 0; r < 16; ++r) { ctx0[r] = 0.f; ctx1[r] = 0.f; }
    float m_i = -1e30f, l_i = 0.f;
    int qglob = q0 + w * 32 + ln31;
    const ushort* mrow = mb + (size_t)qglob * SEQ;

    int sr = tid >> 2, sco = (tid & 3) * 16;
    const ushort* kh_s = Khg + (brow + sr) * DM + hcol + sco;
    const ushort* kl_s = Klg + (brow + sr) * DM + hcol + sco;
    const ushort* vt_s = Vtg + ((size_t)bh * DKH + sr) * SEQ + sco;

    for (int kt = 0; kt < SEQ / 64; ++kt) {
        __syncthreads();
        {
            const ushort* p1 = kh_s + (size_t)kt * 64 * DM;
            const ushort* p2 = kl_s + (size_t)kt * 64 * DM;
            const ushort* p3 = vt_s + kt * 64;
            *(float4*)swz(KhL, sr, sco) = *(const float4*)(p1);
            *(float4*)swz(KhL, sr, sco + 8) = *(const float4*)(p1 + 8);
            *(float4*)swz(KlL, sr, sco) = *(const float4*)(p2);
            *(float4*)swz(KlL, sr, sco + 8) = *(const float4*)(p2 + 8);
            *(float4*)swz(VtL, sr, sco) = *(const float4*)(p3);
            *(float4*)swz(VtL, sr, sco + 8) = *(const float4*)(p3 + 8);
        }
        __syncthreads();

        #pragma unroll
        for (int ksub = 0; ksub < 2; ++ksub) {
            f32x16 s;
            #pragma unroll
            for (int r = 0; r < 16; ++r) s[r] = 0.f;
            __builtin_amdgcn_s_setprio(1);
            #pragma unroll
            for (int c = 0; c < 4; ++c) {
                bf16x8 ka = *(bf16x8*)swz(KhL, ksub * 32 + ln31, c * 16 + hi * 8);
                bf16x8 kb = *(bf16x8*)swz(KlL, ksub * 32 + ln31, c * 16 + hi * 8);
                s = __builtin_amdgcn_mfma_f32_32x32x16_bf16(ka, qfh[c], s, 0, 0, 0);
                s = __builtin_amdgcn_mfma_f32_32x32x16_bf16(ka, qfl[c], s, 0, 0, 0);
                s = __builtin_amdgcn_mfma_f32_32x32x16_bf16(kb, qfh[c], s, 0, 0, 0);
            }
            __builtin_amdgcn_s_setprio(0);
            float tmax = -1e30f;
            #pragma unroll
            for (int rg = 0; rg < 4; ++rg) {
                ushort4 mv = *(const ushort4*)(mrow + kt * 64 + ksub * 32 + rg * 8 + hi * 4);
                ushort mu[4] = {mv.x, mv.y, mv.z, mv.w};
                #pragma unroll
                for (int j = 0; j < 4; ++j) {
                    int r = rg * 4 + j;
                    float sc = floorf(s[r] * 0.125f) + bf2f(mu[j]);
                    s[r] = sc;
                    tmax = fmaxf(tmax, sc);
                }
            }
            tmax = fmaxf(tmax, __shfl_xor(tmax, 32));
            if (!__all(tmax <= m_i)) {
                float newm = fmaxf(m_i, tmax);
                float scl = __expf(m_i - newm);
                m_i = newm;
                l_i *= scl;
                #pragma unroll
                for (int r = 0; r < 16; ++r) { ctx0[r] *= scl; ctx1[r] *= scl; }
            }
            float psum = 0.f;
            #pragma unroll
            for (int r = 0; r < 16; ++r) {
                float p = __expf(s[r] - m_i);
                s[r] = p;
                psum += p;
            }
            psum += __shfl_xor(psum, 32);
            l_i += psum;
            #pragma unroll
            for (int rg = 0; rg < 4; ++rg) {
                uint2 pk;
                pk.x = cvtpk_bf16(s[rg * 4 + 0], s[rg * 4 + 1]);
                pk.y = cvtpk_bf16(s[rg * 4 + 2], s[rg * 4 + 3]);
                *(uint2*)swz(PqW, ln31, ksub * 32 + rg * 8 + hi * 4) = pk;
            }
            __builtin_amdgcn_s_setprio(1);
            #pragma unroll
            for (int cc = 0; cc < 2; ++cc) {
                int c = ksub * 2 + cc;
                bf16x8 pb  = *(bf16x8*)swz(PqW, ln31, c * 16 + hi * 8);
                bf16x8 va0 = *(bf16x8*)swz(VtL, ln31, c * 16 + hi * 8);
                bf16x8 va1 = *(bf16x8*)swz(VtL, 32 + ln31, c * 16 + hi * 8);
                ctx0 = __builtin_amdgcn_mfma_f32_32x32x16_bf16(va0, pb, ctx0, 0, 0, 0);
                ctx1 = __builtin_amdgcn_mfma_f32_32x32x16_bf16(va1, pb, ctx1, 0, 0, 0);
            }
            __builtin_amdgcn_s_setprio(0);
        }
    }

    float inv = 1.0f / l_i;
    ushort* op = O + (brow + qglob) * DM + hcol;
    #pragma unroll
    for (int r = 0; r < 16; ++r) {
        int d = (r & 3) + 8 * (r >> 2) + 4 * hi;
        op[d] = f2bf(ctx0[r] * inv);
        op[32 + d] = f2bf(ctx1[r] * inv);
    }
}

// ---------------------------------------------------------------------------
extern "C" void kernel_launch(void* const* d_in, const int* in_sizes, int n_in,
                              void* d_out, int out_size, void* d_ws, size_t ws_size,
                              hipStream_t stream) {
    const float* x    = (const float*)d_in[0];
    const int*   mask = (const int*)d_in[1];
    const float* wq = (const float*)d_in[2];
    const float* bq = (const float*)d_in[3];
    const float* wk = (const float*)d_in[4];
    const float* bk = (const float*)d_in[5];
    const float* wv = (const float*)d_in[6];
    const float* bv = (const float*)d_in[7];
    const float* wo = (const float*)d_in[8];
    const float* bo = (const float*)d_in[9];
    const float* w1 = (const float*)d_in[10];
    const float* b1 = (const float*)d_in[11];
    const float* w2 = (const float*)d_in[12];
    const float* b2 = (const float*)d_in[13];
    const float* g1  = (const float*)d_in[14];
    const float* be1 = (const float*)d_in[15];
    const float* g2  = (const float*)d_in[16];
    const float* be2 = (const float*)d_in[17];
    float* out = (float*)d_out;

    char* ws = (char*)d_ws;
    const size_t MiB = 1024 * 1024;
    ushort* xn_h = (ushort*)(ws);                 // 8 MiB
    ushort* xn_l = (ushort*)(ws + 8 * MiB);       // 8 MiB
    ushort* q_h  = (ushort*)(ws + 16 * MiB);      // 8 MiB
    ushort* q_l  = (ushort*)(ws + 24 * MiB);      // 8 MiB
    ushort* k_h  = (ushort*)(ws + 32 * MiB);      // 8 MiB
    ushort* k_l  = (ushort*)(ws + 40 * MiB);      // 8 MiB
    ushort* v_h  = (ushort*)(ws + 48 * MiB);      // 8 MiB
    ushort* v_t  = (ushort*)(ws + 56 * MiB);      // 8 MiB
    ushort* wqt_h = (ushort*)(ws + 64 * MiB);
    ushort* wqt_l = (ushort*)(ws + 64 * MiB + 512 * 1024);
    ushort* wkt_h = (ushort*)(ws + 65 * MiB);
    ushort* wkt_l = (ushort*)(ws + 65 * MiB + 512 * 1024);
    ushort* wvt_h = (ushort*)(ws + 66 * MiB);
    ushort* wot_h = (ushort*)(ws + 66 * MiB + 512 * 1024);
    ushort* w1t_h = (ushort*)(ws + 67 * MiB);     // 2 MiB
    ushort* w2t_h = (ushort*)(ws + 69 * MiB);     // 2 MiB
    ushort* mb    = (ushort*)(ws + 71 * MiB);     // 8 MiB
    // overlays
    ushort* ctx  = xn_h;                          // after V gemm
    ushort* xn2  = xn_l;                          // after V gemm
    ushort* ff1  = q_h;                           // 32 MiB over q,k (dead post-attn)

    dim3 blk256(256);
    wconv<true ><<<dim3(8, 8),  blk256, 0, stream>>>(wq, wqt_h, wqt_l, DM, DM);
    wconv<true ><<<dim3(8, 8),  blk256, 0, stream>>>(wk, wkt_h, wkt_l, DM, DM);
    wconv<false><<<dim3(8, 8),  blk256, 0, stream>>>(wv, wvt_h, nullptr, DM, DM);
    wconv<false><<<dim3(8, 8),  blk256, 0, stream>>>(wo, wot_h, nullptr, DM, DM);
    wconv<false><<<dim3(8, 32), blk256, 0, stream>>>(w1, w1t_h, nullptr, DM, DFF);
    wconv<false><<<dim3(32, 8), blk256, 0, stream>>>(w2, w2t_h, nullptr, DFF, DM);
    maskprep<<<SEQ * SEQ / 8 / 256, blk256, 0, stream>>>(mask, mb);
    ln_kernel<true><<<NROWS, 64, 0, stream>>>(x, g1, be1, xn_h, xn_l);
    {
        dim3 grid(DM / 128, NROWS / 128);
        mgemm<3,false,false,2><<<grid, blk256, 0, stream>>>(
            xn_h, xn_l, wqt_h, wqt_l, bq, nullptr, nullptr, q_h, q_l, NROWS, DM, DM);
        mgemm<3,false,false,2><<<grid, blk256, 0, stream>>>(
            xn_h, xn_l, wkt_h, wkt_l, bk, nullptr, nullptr, k_h, k_l, NROWS, DM, DM);
        mgemm<1,false,false,1><<<grid, blk256, 0, stream>>>(
            xn_h, nullptr, wvt_h, nullptr, bv, nullptr, nullptr, v_h, nullptr, NROWS, DM, DM);
    }
    vtrans<<<dim3(SEQ / 64, 4 * NH), blk256, 0, stream>>>(v_h, v_t);
    {
        dim3 grid(SEQ / 128, 4 * NH);
        attn_kernel<<<grid, blk256, 0, stream>>>(q_h, q_l, k_h, k_l, v_t, mb, ctx);
    }
    {
        dim3 grid(DM / 128, NROWS / 128);
        mgemm<1,false,true,0><<<grid, blk256, 0, stream>>>(
            ctx, nullptr, wot_h, nullptr, bo, x, out, nullptr, nullptr, NROWS, DM, DM);
    }
    ln_kernel<false><<<NROWS, 64, 0, stream>>>(out, g2, be2, xn2, nullptr);
    {
        dim3 grid(DFF / 128, NROWS / 128);
        mgemm<1,true,false,1><<<grid, blk256, 0, stream>>>(
            xn2, nullptr, w1t_h, nullptr, b1, nullptr, nullptr, ff1, nullptr, NROWS, DFF, DM);
    }
    {
        dim3 grid(DM / 128, NROWS / 128);
        mgemm<1,false,true,0><<<grid, blk256, 0, stream>>>(
            ff1, nullptr, w2t_h, nullptr, b2, out, out, nullptr, nullptr, NROWS, DM, DFF);
    }
}

// Round 5
// 253.771 us; speedup vs baseline: 8.9757x; 1.3160x over previous
//
#include <hip/hip_runtime.h>
#include <cmath>

#define SEQ 2048
#define DM 512
#define DFF 2048
#define NH 8
#define DKH 64
#define NROWS 8192  // B*S = 4*2048

typedef __attribute__((ext_vector_type(8))) short bf16x8;
typedef __attribute__((ext_vector_type(16))) float f32x16;

__device__ __forceinline__ ushort f2bf(float f) {
    uint u = __float_as_uint(f);
    u += 0x7fff + ((u >> 16) & 1);
    return (ushort)(u >> 16);
}
__device__ __forceinline__ float bf2f(ushort h) {
    return __uint_as_float(((uint)h) << 16);
}
__device__ __forceinline__ uint cvtpk_bf16(float a, float b) {
    uint r;
    asm("v_cvt_pk_bf16_f32 %0, %1, %2" : "=v"(r) : "v"(a), "v"(b));
    return r;
}
// async global->LDS, 16B per lane. LDS dest = base + lane*16 (linear).
__device__ __forceinline__ void gl_lds16(const void* g, void* l) {
    __builtin_amdgcn_global_load_lds(
        (const __attribute__((address_space(1))) void*)g,
        (__attribute__((address_space(3))) void*)l, 16, 0, 0);
}
// 128B-row LDS swizzle (attn): byte ^= (row&7)<<4
__device__ __forceinline__ void* swz(char* base, int row, int col) {
    int byte = (row << 7) + (col << 1);
    byte ^= (row & 7) << 4;
    return base + byte;
}
// gemm LDS swizzle: byte ^= ((row>>2)&7)<<4
__device__ __forceinline__ void* swzg(char* base, int row, int k) {
    int byte = (row << 7) + (k << 1);
    byte ^= ((row >> 2) & 7) << 4;
    return base + byte;
}

// ---------------------------------------------------------------------------
// LayerNorm -> bf16 (hi, optional lo)
// ---------------------------------------------------------------------------
template<bool SPLIT>
__global__ __launch_bounds__(64) void ln_kernel(const float* __restrict__ x,
        const float* __restrict__ g, const float* __restrict__ b,
        ushort* __restrict__ oh, ushort* __restrict__ ol) {
    int row = blockIdx.x;
    int t = threadIdx.x;
    const float* xr = x + (size_t)row * DM + t * 8;
    float v[8];
    *(float4*)&v[0] = *(const float4*)(xr);
    *(float4*)&v[4] = *(const float4*)(xr + 4);
    float s = 0.f;
    #pragma unroll
    for (int j = 0; j < 8; ++j) s += v[j];
    #pragma unroll
    for (int m = 32; m > 0; m >>= 1) s += __shfl_xor(s, m);
    float mean = s * (1.0f / DM);
    float ss = 0.f;
    #pragma unroll
    for (int j = 0; j < 8; ++j) { float d = v[j] - mean; ss += d * d; }
    #pragma unroll
    for (int m = 32; m > 0; m >>= 1) ss += __shfl_xor(ss, m);
    float inv = 1.0f / (sqrtf(ss * (1.0f / (DM - 1))) + 1e-6f);
    float gv[8], bv[8];
    *(float4*)&gv[0] = *(const float4*)(g + t * 8);
    *(float4*)&gv[4] = *(const float4*)(g + t * 8 + 4);
    *(float4*)&bv[0] = *(const float4*)(b + t * 8);
    *(float4*)&bv[4] = *(const float4*)(b + t * 8 + 4);
    union { ushort us[8]; float4 f4; } ph, pl;
    #pragma unroll
    for (int j = 0; j < 8; ++j) {
        float o = gv[j] * (v[j] - mean) * inv + bv[j];
        ushort hb = f2bf(o);
        ph.us[j] = hb;
        if (SPLIT) pl.us[j] = f2bf(o - bf2f(hb));
    }
    *(float4*)(oh + (size_t)row * DM + t * 8) = ph.f4;
    if (SPLIT) *(float4*)(ol + (size_t)row * DM + t * 8) = pl.f4;
}

// ---------------------------------------------------------------------------
// Weight transpose+convert: W[K][N] fp32 -> Wt[N][K] bf16 (hi, optional lo)
// ---------------------------------------------------------------------------
template<bool SPLIT>
__global__ __launch_bounds__(256) void wconv(const float* __restrict__ W,
        ushort* __restrict__ Th, ushort* __restrict__ Tl, int K, int N) {
    __shared__ float tile[64][65];
    int k0 = blockIdx.x * 64, n0 = blockIdx.y * 64;
    int t = threadIdx.x;
    {
        int kr = t >> 2, c0 = (t & 3) * 16;
        const float* src = W + (size_t)(k0 + kr) * N + n0 + c0;
        #pragma unroll
        for (int j = 0; j < 4; ++j)
            *(float4*)&tile[kr][c0 + j * 4] = *(const float4*)(src + j * 4);
    }
    __syncthreads();
    int n = t >> 2, kc = (t & 3) * 16;
    union { ushort us[16]; float4 f4[2]; } ph, pl;
    #pragma unroll
    for (int j = 0; j < 16; ++j) {
        float v = tile[kc + j][n];
        ushort hb = f2bf(v);
        ph.us[j] = hb;
        if (SPLIT) pl.us[j] = f2bf(v - bf2f(hb));
    }
    ushort* dh = Th + (size_t)(n0 + n) * K + k0 + kc;
    *(float4*)(dh) = ph.f4[0];
    *(float4*)(dh + 8) = ph.f4[1];
    if (SPLIT) {
        ushort* dl = Tl + (size_t)(n0 + n) * K + k0 + kc;
        *(float4*)(dl) = pl.f4[0];
        *(float4*)(dl + 8) = pl.f4[1];
    }
}

// ---------------------------------------------------------------------------
// V transpose: vh[(b*SEQ+s)][DM] bf16 (head h cols) -> vt[(bh*64+d)][SEQ] bf16
// ---------------------------------------------------------------------------
__global__ __launch_bounds__(256) void vtrans(const ushort* __restrict__ vh,
        ushort* __restrict__ vt) {
    __shared__ __align__(16) char tile[8192];
    int s0 = blockIdx.x * 64;
    int bh = blockIdx.y;
    int b = bh >> 3, h = bh & 7;
    int t = threadIdx.x;
    {
        int r = t >> 2, co = (t & 3) * 16;
        const ushort* src = vh + (size_t)(b * SEQ + s0 + r) * DM + h * DKH + co;
        *(float4*)swz(tile, r, co) = *(const float4*)(src);
        *(float4*)swz(tile, r, co + 8) = *(const float4*)(src + 8);
    }
    __syncthreads();
    int d = t >> 2, j0 = (t & 3) * 16;
    union { ushort us[16]; float4 f4[2]; } o;
    #pragma unroll
    for (int j = 0; j < 16; ++j)
        o.us[j] = *(ushort*)swz(tile, j0 + j, d);
    ushort* dst = vt + ((size_t)bh * DKH + d) * SEQ + s0 + j0;
    *(float4*)(dst) = o.f4[0];
    *(float4*)(dst + 8) = o.f4[1];
}

// ---------------------------------------------------------------------------
// Mask -> additive bf16 bias {0, -1e9}
// ---------------------------------------------------------------------------
__global__ __launch_bounds__(256) void maskprep(const int* __restrict__ mask,
        ushort* __restrict__ mb) {
    int i = (blockIdx.x * 256 + threadIdx.x) * 8;
    int4 a = *(const int4*)(mask + i);
    int4 c = *(const int4*)(mask + i + 4);
    ushort neg = f2bf(-1e9f);
    union { ushort us[8]; float4 f4; } o;
    o.us[0] = a.x ? (ushort)0 : neg;
    o.us[1] = a.y ? (ushort)0 : neg;
    o.us[2] = a.z ? (ushort)0 : neg;
    o.us[3] = a.w ? (ushort)0 : neg;
    o.us[4] = c.x ? (ushort)0 : neg;
    o.us[5] = c.y ? (ushort)0 : neg;
    o.us[6] = c.z ? (ushort)0 : neg;
    o.us[7] = c.w ? (ushort)0 : neg;
    *(float4*)(mb + i) = o.f4;
}

// ---------------------------------------------------------------------------
// 1-term MFMA GEMM, double-buffered via global_load_lds prefetch.
// C = A @ Bt^T + bias (+resid)(+relu). OUT: 0=f32, 1=bf16.
// ---------------------------------------------------------------------------
template<bool RELU, bool HASRES, int OUT>
__global__ __launch_bounds__(256) void mgemm(
        const ushort* __restrict__ Ah, const ushort* __restrict__ Bth,
        const float* __restrict__ bias, const float* __restrict__ resid,
        float* __restrict__ Cf, ushort* __restrict__ Cbh,
        int M, int N, int K) {
    __shared__ __align__(16) char smem[65536];
    int tid = threadIdx.x;
    int lane = tid & 63, w = tid >> 6;
    int ln31 = lane & 31, hi = lane >> 5;
    int mh = (w >> 1) * 64, nh = (w & 1) * 64;
    int gx = gridDim.x;
    int nwg = gx * gridDim.y;
    int flat = blockIdx.y * gx + blockIdx.x;
    int sid = (flat & 7) * (nwg >> 3) + (flat >> 3);
    int n0 = (sid % gx) * 128;
    int m0 = (sid / gx) * 128;

    f32x16 acc[2][2];
    #pragma unroll
    for (int i = 0; i < 2; ++i)
        #pragma unroll
        for (int j = 0; j < 2; ++j)
            #pragma unroll
            for (int r = 0; r < 16; ++r) acc[i][j][r] = 0.f;

    // stage A/B tile (16 chunks of 1KB each) into given buffers
    auto stage = [&](char* Abuf, char* Bbuf, int k0) {
        #pragma unroll
        for (int c = 0; c < 4; ++c) {
            int ch = w * 4 + c;
            int r = ch * 8 + (lane >> 3);
            int u = (lane & 7) ^ ((r >> 2) & 7);
            gl_lds16(Ah + (size_t)(m0 + r) * K + k0 + u * 8, Abuf + ch * 1024);
            gl_lds16(Bth + (size_t)(n0 + r) * K + k0 + u * 8, Bbuf + ch * 1024);
        }
    };

    char* A0 = smem;
    char* B0 = smem + 16384;
    char* A1 = smem + 32768;
    char* B1 = smem + 49152;

    stage(A0, B0, 0);
    __syncthreads();
    int nk = K / 64;
    for (int kt = 0; kt < nk; ++kt) {
        char* Ac = (kt & 1) ? A1 : A0;
        char* Bc = (kt & 1) ? B1 : B0;
        if (kt + 1 < nk)
            stage((kt & 1) ? A0 : A1, (kt & 1) ? B0 : B1, (kt + 1) * 64);
        __builtin_amdgcn_s_setprio(1);
        #pragma unroll
        for (int km = 0; km < 4; ++km) {
            int kk = km * 16 + hi * 8;
            bf16x8 ah[2], bh[2];
            ah[0] = *(bf16x8*)swzg(Ac, mh + ln31, kk);
            ah[1] = *(bf16x8*)swzg(Ac, mh + 32 + ln31, kk);
            bh[0] = *(bf16x8*)swzg(Bc, nh + ln31, kk);
            bh[1] = *(bf16x8*)swzg(Bc, nh + 32 + ln31, kk);
            #pragma unroll
            for (int mi = 0; mi < 2; ++mi)
                #pragma unroll
                for (int ni = 0; ni < 2; ++ni)
                    acc[mi][ni] = __builtin_amdgcn_mfma_f32_32x32x16_bf16(
                        ah[mi], bh[ni], acc[mi][ni], 0, 0, 0);
        }
        __builtin_amdgcn_s_setprio(0);
        __syncthreads();
    }
    float bv[2];
    bv[0] = bias[n0 + nh + ln31];
    bv[1] = bias[n0 + nh + 32 + ln31];
    #pragma unroll
    for (int mi = 0; mi < 2; ++mi)
        #pragma unroll
        for (int ni = 0; ni < 2; ++ni) {
            int n = n0 + nh + ni * 32 + ln31;
            #pragma unroll
            for (int r = 0; r < 16; ++r) {
                int m = m0 + mh + mi * 32 + (r & 3) + 8 * (r >> 2) + 4 * hi;
                float v = acc[mi][ni][r] + bv[ni];
                if (HASRES) v += resid[(size_t)m * N + n];
                if (RELU) v = fmaxf(v, 0.f);
                size_t idx = (size_t)m * N + n;
                if (OUT == 0) Cf[idx] = v;
                else Cbh[idx] = f2bf(v);
            }
        }
}

// ---------------------------------------------------------------------------
// Fused QKV GEMM: A[8192,512] (split bf16) @ Wqkv[1536,512]^T.
// Q,K blocks (n0<1024): 3-term split, split bf16 output.
// V blocks (n0>=1024): 1-term, bf16 output. Single-buffer m97-style.
// ---------------------------------------------------------------------------
__global__ __launch_bounds__(256) void qkv_gemm(
        const ushort* __restrict__ Ah, const ushort* __restrict__ Al,
        const ushort* __restrict__ Bth, const ushort* __restrict__ Btl,
        const float* __restrict__ bq, const float* __restrict__ bk,
        const float* __restrict__ bv_, ushort* __restrict__ q_h,
        ushort* __restrict__ q_l, ushort* __restrict__ k_h,
        ushort* __restrict__ k_l, ushort* __restrict__ v_h) {
    const int K = DM, N = DM;  // A row-len 512; per-target output col-len 512
    __shared__ __align__(16) char smem[65536];
    char* As_h = smem;
    char* Bs_h = smem + 16384;
    char* As_l = smem + 32768;
    char* Bs_l = smem + 49152;
    int tid = threadIdx.x;
    int lane = tid & 63, w = tid >> 6;
    int ln31 = lane & 31, hi = lane >> 5;
    int mh = (w >> 1) * 64, nh = (w & 1) * 64;
    int gx = gridDim.x;  // 12
    int nwg = gx * gridDim.y;
    int flat = blockIdx.y * gx + blockIdx.x;
    int sid = (flat & 7) * (nwg >> 3) + (flat >> 3);
    int n0 = (sid % gx) * 128;
    int m0 = (sid / gx) * 128;
    bool isqk = (n0 < 1024);

    f32x16 acc[2][2];
    #pragma unroll
    for (int i = 0; i < 2; ++i)
        #pragma unroll
        for (int j = 0; j < 2; ++j)
            #pragma unroll
            for (int r = 0; r < 16; ++r) acc[i][j][r] = 0.f;

    for (int k0 = 0; k0 < K; k0 += 64) {
        #pragma unroll
        for (int c = 0; c < 4; ++c) {
            int ch = w * 4 + c;
            int r = ch * 8 + (lane >> 3);
            int u = (lane & 7) ^ ((r >> 2) & 7);
            gl_lds16(Ah + (size_t)(m0 + r) * K + k0 + u * 8, As_h + ch * 1024);
            gl_lds16(Bth + (size_t)(n0 + r) * K + k0 + u * 8, Bs_h + ch * 1024);
            if (isqk) {
                gl_lds16(Al + (size_t)(m0 + r) * K + k0 + u * 8, As_l + ch * 1024);
                gl_lds16(Btl + (size_t)(n0 + r) * K + k0 + u * 8, Bs_l + ch * 1024);
            }
        }
        __syncthreads();
        __builtin_amdgcn_s_setprio(1);
        #pragma unroll
        for (int km = 0; km < 4; ++km) {
            int kk = km * 16 + hi * 8;
            bf16x8 ah[2], bh[2];
            ah[0] = *(bf16x8*)swzg(As_h, mh + ln31, kk);
            ah[1] = *(bf16x8*)swzg(As_h, mh + 32 + ln31, kk);
            bh[0] = *(bf16x8*)swzg(Bs_h, nh + ln31, kk);
            bh[1] = *(bf16x8*)swzg(Bs_h, nh + 32 + ln31, kk);
            if (isqk) {
                bf16x8 al[2], bl[2];
                al[0] = *(bf16x8*)swzg(As_l, mh + ln31, kk);
                al[1] = *(bf16x8*)swzg(As_l, mh + 32 + ln31, kk);
                bl[0] = *(bf16x8*)swzg(Bs_l, nh + ln31, kk);
                bl[1] = *(bf16x8*)swzg(Bs_l, nh + 32 + ln31, kk);
                #pragma unroll
                for (int mi = 0; mi < 2; ++mi)
                    #pragma unroll
                    for (int ni = 0; ni < 2; ++ni) {
                        acc[mi][ni] = __builtin_amdgcn_mfma_f32_32x32x16_bf16(
                            ah[mi], bh[ni], acc[mi][ni], 0, 0, 0);
                        acc[mi][ni] = __builtin_amdgcn_mfma_f32_32x32x16_bf16(
                            ah[mi], bl[ni], acc[mi][ni], 0, 0, 0);
                        acc[mi][ni] = __builtin_amdgcn_mfma_f32_32x32x16_bf16(
                            al[mi], bh[ni], acc[mi][ni], 0, 0, 0);
                    }
            } else {
                #pragma unroll
                for (int mi = 0; mi < 2; ++mi)
                    #pragma unroll
                    for (int ni = 0; ni < 2; ++ni)
                        acc[mi][ni] = __builtin_amdgcn_mfma_f32_32x32x16_bf16(
                            ah[mi], bh[ni], acc[mi][ni], 0, 0, 0);
            }
        }
        __builtin_amdgcn_s_setprio(0);
        __syncthreads();
    }
    // routing
    const float* bias = (n0 < 512) ? bq : (n0 < 1024 ? bk : bv_);
    int ncol0 = n0 & 511;
    ushort* Oh = (n0 < 512) ? q_h : (n0 < 1024 ? k_h : v_h);
    ushort* Ol = (n0 < 512) ? q_l : (n0 < 1024 ? k_l : nullptr);
    float bvv[2];
    bvv[0] = bias[ncol0 + nh + ln31];
    bvv[1] = bias[ncol0 + nh + 32 + ln31];
    #pragma unroll
    for (int mi = 0; mi < 2; ++mi)
        #pragma unroll
        for (int ni = 0; ni < 2; ++ni) {
            int n = ncol0 + nh + ni * 32 + ln31;
            #pragma unroll
            for (int r = 0; r < 16; ++r) {
                int m = m0 + mh + mi * 32 + (r & 3) + 8 * (r >> 2) + 4 * hi;
                float v = acc[mi][ni][r] + bvv[ni];
                size_t idx = (size_t)m * N + n;
                ushort hb = f2bf(v);
                Oh[idx] = hb;
                if (isqk) Ol[idx] = f2bf(v - bf2f(hb));
            }
        }
}

// ---------------------------------------------------------------------------
// MFMA flash attention with global_load_lds K/V double-buffer prefetch.
// ---------------------------------------------------------------------------
__global__ __launch_bounds__(256, 2) void attn_kernel(
        const ushort* __restrict__ Qh, const ushort* __restrict__ Ql,
        const ushort* __restrict__ Khg, const ushort* __restrict__ Klg,
        const ushort* __restrict__ Vtg, const ushort* __restrict__ mb,
        ushort* __restrict__ O) {
    __shared__ __align__(16) char smem[65536];
    // buf0 @0, buf1 @24K (Kh +0, Kl +8K, Vt +16K each); PqW @48K; Q staging @24K..56K
    int tid = threadIdx.x;
    int w = tid >> 6, lane = tid & 63;
    int ln31 = lane & 31, hi = lane >> 5;
    int f = blockIdx.y * gridDim.x + blockIdx.x;
    int g = (f & 7) * 64 + (f >> 3);
    int qb = g & 15, bh = g >> 4;
    int b = bh >> 3, h = bh & 7;
    int q0 = qb * 128;
    size_t brow = (size_t)b * SEQ;
    int hcol = h * DKH;
    char* PqW = smem + 49152 + w * 4096;

    auto stage_kv = [&](char* buf, int kt) {
        #pragma unroll
        for (int c = 0; c < 2; ++c) {
            int ch = w * 2 + c;
            int r = ch * 8 + (lane >> 3);
            int u = (lane & 7) ^ (r & 7);
            gl_lds16(Khg + (brow + kt * 64 + r) * DM + hcol + u * 8,
                     buf + ch * 1024);
            gl_lds16(Klg + (brow + kt * 64 + r) * DM + hcol + u * 8,
                     buf + 8192 + ch * 1024);
            gl_lds16(Vtg + ((size_t)bh * DKH + r) * SEQ + kt * 64 + u * 8,
                     buf + 16384 + ch * 1024);
        }
    };

    // prologue: issue kt=0 K/V + Q staging, all async
    stage_kv(smem, 0);
    {
        char* QhL = smem + 24576;
        char* QlL = smem + 40960;
        #pragma unroll
        for (int c = 0; c < 4; ++c) {
            int ch = w * 4 + c;
            int r = ch * 8 + (lane >> 3);
            int u = (lane & 7) ^ (r & 7);
            gl_lds16(Qh + (brow + q0 + r) * DM + hcol + u * 8, QhL + ch * 1024);
            gl_lds16(Ql + (brow + q0 + r) * DM + hcol + u * 8, QlL + ch * 1024);
        }
    }
    __syncthreads();
    bf16x8 qfh[4], qfl[4];
    {
        int qr = w * 32 + ln31;
        #pragma unroll
        for (int c = 0; c < 4; ++c) {
            qfh[c] = *(bf16x8*)swz(smem + 24576, qr, c * 16 + hi * 8);
            qfl[c] = *(bf16x8*)swz(smem + 40960, qr, c * 16 + hi * 8);
        }
    }
    __syncthreads();  // Q staging region now reusable as buf1

    f32x16 ctx0, ctx1;
    #pragma unroll
    for (int r = 0; r < 16; ++r) { ctx0[r] = 0.f; ctx1[r] = 0.f; }
    float m_i = -1e30f, l_i = 0.f;
    int qglob = q0 + w * 32 + ln31;
    const ushort* mrow = mb + (size_t)qglob * SEQ;

    for (int kt = 0; kt < SEQ / 64; ++kt) {
        char* cur = smem + (kt & 1) * 24576;
        if (kt + 1 < SEQ / 64)
            stage_kv(smem + ((kt + 1) & 1) * 24576, kt + 1);
        char* KhL = cur;
        char* KlL = cur + 8192;
        char* VtL = cur + 16384;
        #pragma unroll
        for (int ksub = 0; ksub < 2; ++ksub) {
            f32x16 s;
            #pragma unroll
            for (int r = 0; r < 16; ++r) s[r] = 0.f;
            __builtin_amdgcn_s_setprio(1);
            #pragma unroll
            for (int c = 0; c < 4; ++c) {
                bf16x8 ka = *(bf16x8*)swz(KhL, ksub * 32 + ln31, c * 16 + hi * 8);
                bf16x8 kb = *(bf16x8*)swz(KlL, ksub * 32 + ln31, c * 16 + hi * 8);
                s = __builtin_amdgcn_mfma_f32_32x32x16_bf16(ka, qfh[c], s, 0, 0, 0);
                s = __builtin_amdgcn_mfma_f32_32x32x16_bf16(ka, qfl[c], s, 0, 0, 0);
                s = __builtin_amdgcn_mfma_f32_32x32x16_bf16(kb, qfh[c], s, 0, 0, 0);
            }
            __builtin_amdgcn_s_setprio(0);
            float tmax = -1e30f;
            #pragma unroll
            for (int rg = 0; rg < 4; ++rg) {
                ushort4 mv = *(const ushort4*)(mrow + kt * 64 + ksub * 32 + rg * 8 + hi * 4);
                ushort mu[4] = {mv.x, mv.y, mv.z, mv.w};
                #pragma unroll
                for (int j = 0; j < 4; ++j) {
                    int r = rg * 4 + j;
                    float sc = floorf(s[r] * 0.125f) + bf2f(mu[j]);
                    s[r] = sc;
                    tmax = fmaxf(tmax, sc);
                }
            }
            tmax = fmaxf(tmax, __shfl_xor(tmax, 32));
            if (!__all(tmax <= m_i)) {
                float newm = fmaxf(m_i, tmax);
                float scl = __expf(m_i - newm);
                m_i = newm;
                l_i *= scl;
                #pragma unroll
                for (int r = 0; r < 16; ++r) { ctx0[r] *= scl; ctx1[r] *= scl; }
            }
            float psum = 0.f;
            #pragma unroll
            for (int r = 0; r < 16; ++r) {
                float p = __expf(s[r] - m_i);
                s[r] = p;
                psum += p;
            }
            psum += __shfl_xor(psum, 32);
            l_i += psum;
            #pragma unroll
            for (int rg = 0; rg < 4; ++rg) {
                uint2 pk;
                pk.x = cvtpk_bf16(s[rg * 4 + 0], s[rg * 4 + 1]);
                pk.y = cvtpk_bf16(s[rg * 4 + 2], s[rg * 4 + 3]);
                *(uint2*)swz(PqW, ln31, ksub * 32 + rg * 8 + hi * 4) = pk;
            }
            __builtin_amdgcn_s_setprio(1);
            #pragma unroll
            for (int cc = 0; cc < 2; ++cc) {
                int c = ksub * 2 + cc;
                bf16x8 pb  = *(bf16x8*)swz(PqW, ln31, c * 16 + hi * 8);
                bf16x8 va0 = *(bf16x8*)swz(VtL, ln31, c * 16 + hi * 8);
                bf16x8 va1 = *(bf16x8*)swz(VtL, 32 + ln31, c * 16 + hi * 8);
                ctx0 = __builtin_amdgcn_mfma_f32_32x32x16_bf16(va0, pb, ctx0, 0, 0, 0);
                ctx1 = __builtin_amdgcn_mfma_f32_32x32x16_bf16(va1, pb, ctx1, 0, 0, 0);
            }
            __builtin_amdgcn_s_setprio(0);
        }
        __syncthreads();  // next tile staged; current fully consumed
    }

    float inv = 1.0f / l_i;
    ushort* op = O + (brow + qglob) * DM + hcol;
    #pragma unroll
    for (int r = 0; r < 16; ++r) {
        int d = (r & 3) + 8 * (r >> 2) + 4 * hi;
        op[d] = f2bf(ctx0[r] * inv);
        op[32 + d] = f2bf(ctx1[r] * inv);
    }
}

// ---------------------------------------------------------------------------
extern "C" void kernel_launch(void* const* d_in, const int* in_sizes, int n_in,
                              void* d_out, int out_size, void* d_ws, size_t ws_size,
                              hipStream_t stream) {
    const float* x    = (const float*)d_in[0];
    const int*   mask = (const int*)d_in[1];
    const float* wq = (const float*)d_in[2];
    const float* bq = (const float*)d_in[3];
    const float* wk = (const float*)d_in[4];
    const float* bk = (const float*)d_in[5];
    const float* wv = (const float*)d_in[6];
    const float* bv = (const float*)d_in[7];
    const float* wo = (const float*)d_in[8];
    const float* bo = (const float*)d_in[9];
    const float* w1 = (const float*)d_in[10];
    const float* b1 = (const float*)d_in[11];
    const float* w2 = (const float*)d_in[12];
    const float* b2 = (const float*)d_in[13];
    const float* g1  = (const float*)d_in[14];
    const float* be1 = (const float*)d_in[15];
    const float* g2  = (const float*)d_in[16];
    const float* be2 = (const float*)d_in[17];
    float* out = (float*)d_out;

    char* ws = (char*)d_ws;
    const size_t MiB = 1024 * 1024;
    ushort* xn_h = (ushort*)(ws);                 // 8 MiB
    ushort* xn_l = (ushort*)(ws + 8 * MiB);       // 8 MiB
    ushort* q_h  = (ushort*)(ws + 16 * MiB);      // 8 MiB
    ushort* q_l  = (ushort*)(ws + 24 * MiB);      // 8 MiB
    ushort* k_h  = (ushort*)(ws + 32 * MiB);      // 8 MiB
    ushort* k_l  = (ushort*)(ws + 40 * MiB);      // 8 MiB
    ushort* v_h  = (ushort*)(ws + 48 * MiB);      // 8 MiB
    ushort* v_t  = (ushort*)(ws + 56 * MiB);      // 8 MiB
    ushort* wqkvt_h = (ushort*)(ws + 64 * MiB);   // [1536][512] bf16, 1.5 MiB
    ushort* wqkvt_l = (ushort*)(ws + 66 * MiB);   // [1024][512] bf16, 1 MiB
    ushort* wot_h = (ushort*)(ws + 67 * MiB);     // 512 KiB
    ushort* w1t_h = (ushort*)(ws + 68 * MiB);     // 2 MiB
    ushort* w2t_h = (ushort*)(ws + 70 * MiB);     // 2 MiB
    ushort* mb    = (ushort*)(ws + 72 * MiB);     // 8 MiB
    // overlays
    ushort* ctx  = xn_h;                          // after qkv
    ushort* xn2  = xn_l;                          // after qkv
    ushort* ff1  = q_h;                           // 32 MiB over q,k (dead post-attn)

    dim3 blk256(256);
    wconv<true ><<<dim3(8, 8),  blk256, 0, stream>>>(wq, wqkvt_h, wqkvt_l, DM, DM);
    wconv<true ><<<dim3(8, 8),  blk256, 0, stream>>>(wk, wqkvt_h + 512 * 512, wqkvt_l + 512 * 512, DM, DM);
    wconv<false><<<dim3(8, 8),  blk256, 0, stream>>>(wv, wqkvt_h + 1024 * 512, nullptr, DM, DM);
    wconv<false><<<dim3(8, 8),  blk256, 0, stream>>>(wo, wot_h, nullptr, DM, DM);
    wconv<false><<<dim3(8, 32), blk256, 0, stream>>>(w1, w1t_h, nullptr, DM, DFF);
    wconv<false><<<dim3(32, 8), blk256, 0, stream>>>(w2, w2t_h, nullptr, DFF, DM);
    maskprep<<<SEQ * SEQ / 8 / 256, blk256, 0, stream>>>(mask, mb);
    ln_kernel<true><<<NROWS, 64, 0, stream>>>(x, g1, be1, xn_h, xn_l);
    // fused QKV
    qkv_gemm<<<dim3(12, NROWS / 128), blk256, 0, stream>>>(
        xn_h, xn_l, wqkvt_h, wqkvt_l, bq, bk, bv, q_h, q_l, k_h, k_l, v_h);
    vtrans<<<dim3(SEQ / 64, 4 * NH), blk256, 0, stream>>>(v_h, v_t);
    {
        dim3 grid(SEQ / 128, 4 * NH);
        attn_kernel<<<grid, blk256, 0, stream>>>(q_h, q_l, k_h, k_l, v_t, mb, ctx);
    }
    {
        dim3 grid(DM / 128, NROWS / 128);
        mgemm<false,true,0><<<grid, blk256, 0, stream>>>(
            ctx, wot_h, bo, x, out, nullptr, NROWS, DM, DM);
    }
    ln_kernel<false><<<NROWS, 64, 0, stream>>>(out, g2, be2, xn2, nullptr);
    {
        dim3 grid(DFF / 128, NROWS / 128);
        mgemm<true,false,1><<<grid, blk256, 0, stream>>>(
            xn2, w1t_h, b1, nullptr, nullptr, ff1, NROWS, DFF, DM);
    }
    {
        dim3 grid(DM / 128, NROWS / 128);
        mgemm<false,true,0><<<grid, blk256, 0, stream>>>(
            ff1, w2t_h, b2, out, out, nullptr, NROWS, DM, DFF);
    }
}

// Round 6
// 240.724 us; speedup vs baseline: 9.4622x; 1.0542x over previous
//
#include <hip/hip_runtime.h>
#include <cmath>

#define SEQ 2048
#define DM 512
#define DFF 2048
#define NH 8
#define DKH 64
#define NROWS 8192  // B*S = 4*2048

typedef __attribute__((ext_vector_type(8))) short bf16x8;
typedef __attribute__((ext_vector_type(16))) float f32x16;

__device__ __forceinline__ ushort f2bf(float f) {
    uint u = __float_as_uint(f);
    u += 0x7fff + ((u >> 16) & 1);
    return (ushort)(u >> 16);
}
__device__ __forceinline__ float bf2f(ushort h) {
    return __uint_as_float(((uint)h) << 16);
}
__device__ __forceinline__ uint cvtpk_bf16(float a, float b) {
    uint r;
    asm("v_cvt_pk_bf16_f32 %0, %1, %2" : "=v"(r) : "v"(a), "v"(b));
    return r;
}
// async global->LDS, 16B per lane. LDS dest = base + lane*16 (linear).
__device__ __forceinline__ void gl_lds16(const void* g, void* l) {
    __builtin_amdgcn_global_load_lds(
        (const __attribute__((address_space(1))) void*)g,
        (__attribute__((address_space(3))) void*)l, 16, 0, 0);
}
// 128B-row LDS swizzle (attn): byte ^= (row&7)<<4
__device__ __forceinline__ void* swz(char* base, int row, int col) {
    int byte = (row << 7) + (col << 1);
    byte ^= (row & 7) << 4;
    return base + byte;
}
// gemm LDS swizzle: byte ^= ((row>>2)&7)<<4
__device__ __forceinline__ void* swzg(char* base, int row, int k) {
    int byte = (row << 7) + (k << 1);
    byte ^= ((row >> 2) & 7) << 4;
    return base + byte;
}

// ---------------------------------------------------------------------------
// LayerNorm -> bf16 (hi, optional lo)
// ---------------------------------------------------------------------------
template<bool SPLIT>
__global__ __launch_bounds__(64) void ln_kernel(const float* __restrict__ x,
        const float* __restrict__ g, const float* __restrict__ b,
        ushort* __restrict__ oh, ushort* __restrict__ ol) {
    int row = blockIdx.x;
    int t = threadIdx.x;
    const float* xr = x + (size_t)row * DM + t * 8;
    float v[8];
    *(float4*)&v[0] = *(const float4*)(xr);
    *(float4*)&v[4] = *(const float4*)(xr + 4);
    float s = 0.f;
    #pragma unroll
    for (int j = 0; j < 8; ++j) s += v[j];
    #pragma unroll
    for (int m = 32; m > 0; m >>= 1) s += __shfl_xor(s, m);
    float mean = s * (1.0f / DM);
    float ss = 0.f;
    #pragma unroll
    for (int j = 0; j < 8; ++j) { float d = v[j] - mean; ss += d * d; }
    #pragma unroll
    for (int m = 32; m > 0; m >>= 1) ss += __shfl_xor(ss, m);
    float inv = 1.0f / (sqrtf(ss * (1.0f / (DM - 1))) + 1e-6f);
    float gv[8], bv[8];
    *(float4*)&gv[0] = *(const float4*)(g + t * 8);
    *(float4*)&gv[4] = *(const float4*)(g + t * 8 + 4);
    *(float4*)&bv[0] = *(const float4*)(b + t * 8);
    *(float4*)&bv[4] = *(const float4*)(b + t * 8 + 4);
    union { ushort us[8]; float4 f4; } ph, pl;
    #pragma unroll
    for (int j = 0; j < 8; ++j) {
        float o = gv[j] * (v[j] - mean) * inv + bv[j];
        ushort hb = f2bf(o);
        ph.us[j] = hb;
        if (SPLIT) pl.us[j] = f2bf(o - bf2f(hb));
    }
    *(float4*)(oh + (size_t)row * DM + t * 8) = ph.f4;
    if (SPLIT) *(float4*)(ol + (size_t)row * DM + t * 8) = pl.f4;
}

// ---------------------------------------------------------------------------
// Merged weight transpose+convert for the four 512x512 weights.
// z=0: wq (split), z=1: wk (split), z=2: wv, z=3: wo.
// ---------------------------------------------------------------------------
__global__ __launch_bounds__(256) void wconv4(
        const float* __restrict__ wq, const float* __restrict__ wk,
        const float* __restrict__ wv, const float* __restrict__ wo,
        ushort* __restrict__ qh, ushort* __restrict__ ql,
        ushort* __restrict__ kh, ushort* __restrict__ kl,
        ushort* __restrict__ vh, ushort* __restrict__ oh) {
    const int K = DM, N = DM;
    __shared__ float tile[64][65];
    int z = blockIdx.z;
    const float* W = (z == 0) ? wq : (z == 1) ? wk : (z == 2) ? wv : wo;
    ushort* Th = (z == 0) ? qh : (z == 1) ? kh : (z == 2) ? vh : oh;
    ushort* Tl = (z == 0) ? ql : (z == 1) ? kl : nullptr;
    bool split = (z < 2);
    int k0 = blockIdx.x * 64, n0 = blockIdx.y * 64;
    int t = threadIdx.x;
    {
        int kr = t >> 2, c0 = (t & 3) * 16;
        const float* src = W + (size_t)(k0 + kr) * N + n0 + c0;
        #pragma unroll
        for (int j = 0; j < 4; ++j)
            *(float4*)&tile[kr][c0 + j * 4] = *(const float4*)(src + j * 4);
    }
    __syncthreads();
    int n = t >> 2, kc = (t & 3) * 16;
    union { ushort us[16]; float4 f4[2]; } ph, pl;
    #pragma unroll
    for (int j = 0; j < 16; ++j) {
        float v = tile[kc + j][n];
        ushort hb = f2bf(v);
        ph.us[j] = hb;
        pl.us[j] = f2bf(v - bf2f(hb));
    }
    ushort* dh = Th + (size_t)(n0 + n) * K + k0 + kc;
    *(float4*)(dh) = ph.f4[0];
    *(float4*)(dh + 8) = ph.f4[1];
    if (split) {
        ushort* dl = Tl + (size_t)(n0 + n) * K + k0 + kc;
        *(float4*)(dl) = pl.f4[0];
        *(float4*)(dl + 8) = pl.f4[1];
    }
}

// ---------------------------------------------------------------------------
// Weight transpose+convert (single, for w1/w2)
// ---------------------------------------------------------------------------
__global__ __launch_bounds__(256) void wconv(const float* __restrict__ W,
        ushort* __restrict__ Th, int K, int N) {
    __shared__ float tile[64][65];
    int k0 = blockIdx.x * 64, n0 = blockIdx.y * 64;
    int t = threadIdx.x;
    {
        int kr = t >> 2, c0 = (t & 3) * 16;
        const float* src = W + (size_t)(k0 + kr) * N + n0 + c0;
        #pragma unroll
        for (int j = 0; j < 4; ++j)
            *(float4*)&tile[kr][c0 + j * 4] = *(const float4*)(src + j * 4);
    }
    __syncthreads();
    int n = t >> 2, kc = (t & 3) * 16;
    union { ushort us[16]; float4 f4[2]; } ph;
    #pragma unroll
    for (int j = 0; j < 16; ++j) ph.us[j] = f2bf(tile[kc + j][n]);
    ushort* dh = Th + (size_t)(n0 + n) * K + k0 + kc;
    *(float4*)(dh) = ph.f4[0];
    *(float4*)(dh + 8) = ph.f4[1];
}

// ---------------------------------------------------------------------------
// V transpose: vh[(b*SEQ+s)][DM] bf16 (head h cols) -> vt[(bh*64+d)][SEQ] bf16
// ---------------------------------------------------------------------------
__global__ __launch_bounds__(256) void vtrans(const ushort* __restrict__ vh,
        ushort* __restrict__ vt) {
    __shared__ __align__(16) char tile[8192];
    int s0 = blockIdx.x * 64;
    int bh = blockIdx.y;
    int b = bh >> 3, h = bh & 7;
    int t = threadIdx.x;
    {
        int r = t >> 2, co = (t & 3) * 16;
        const ushort* src = vh + (size_t)(b * SEQ + s0 + r) * DM + h * DKH + co;
        *(float4*)swz(tile, r, co) = *(const float4*)(src);
        *(float4*)swz(tile, r, co + 8) = *(const float4*)(src + 8);
    }
    __syncthreads();
    int d = t >> 2, j0 = (t & 3) * 16;
    union { ushort us[16]; float4 f4[2]; } o;
    #pragma unroll
    for (int j = 0; j < 16; ++j)
        o.us[j] = *(ushort*)swz(tile, j0 + j, d);
    ushort* dst = vt + ((size_t)bh * DKH + d) * SEQ + s0 + j0;
    *(float4*)(dst) = o.f4[0];
    *(float4*)(dst + 8) = o.f4[1];
}

// ---------------------------------------------------------------------------
// Mask -> additive bf16 bias {0, -1e9}
// ---------------------------------------------------------------------------
__global__ __launch_bounds__(256) void maskprep(const int* __restrict__ mask,
        ushort* __restrict__ mb) {
    int i = (blockIdx.x * 256 + threadIdx.x) * 8;
    int4 a = *(const int4*)(mask + i);
    int4 c = *(const int4*)(mask + i + 4);
    ushort neg = f2bf(-1e9f);
    union { ushort us[8]; float4 f4; } o;
    o.us[0] = a.x ? (ushort)0 : neg;
    o.us[1] = a.y ? (ushort)0 : neg;
    o.us[2] = a.z ? (ushort)0 : neg;
    o.us[3] = a.w ? (ushort)0 : neg;
    o.us[4] = c.x ? (ushort)0 : neg;
    o.us[5] = c.y ? (ushort)0 : neg;
    o.us[6] = c.z ? (ushort)0 : neg;
    o.us[7] = c.w ? (ushort)0 : neg;
    *(float4*)(mb + i) = o.f4;
}

// ---------------------------------------------------------------------------
// 1-term MFMA GEMM, double-buffered via global_load_lds prefetch.
// C = A @ Bt^T + bias (+resid)(+relu). OUT: 0=f32, 1=bf16.
// ---------------------------------------------------------------------------
template<bool RELU, bool HASRES, int OUT>
__global__ __launch_bounds__(256) void mgemm(
        const ushort* __restrict__ Ah, const ushort* __restrict__ Bth,
        const float* __restrict__ bias, const float* __restrict__ resid,
        float* __restrict__ Cf, ushort* __restrict__ Cbh,
        int M, int N, int K) {
    __shared__ __align__(16) char smem[65536];
    int tid = threadIdx.x;
    int lane = tid & 63, w = tid >> 6;
    int ln31 = lane & 31, hi = lane >> 5;
    int mh = (w >> 1) * 64, nh = (w & 1) * 64;
    int gx = gridDim.x;
    int nwg = gx * gridDim.y;
    int flat = blockIdx.y * gx + blockIdx.x;
    int sid = (flat & 7) * (nwg >> 3) + (flat >> 3);
    int n0 = (sid % gx) * 128;
    int m0 = (sid / gx) * 128;

    f32x16 acc[2][2];
    #pragma unroll
    for (int i = 0; i < 2; ++i)
        #pragma unroll
        for (int j = 0; j < 2; ++j)
            #pragma unroll
            for (int r = 0; r < 16; ++r) acc[i][j][r] = 0.f;

    auto stage = [&](char* Abuf, char* Bbuf, int k0) {
        #pragma unroll
        for (int c = 0; c < 4; ++c) {
            int ch = w * 4 + c;
            int r = ch * 8 + (lane >> 3);
            int u = (lane & 7) ^ ((r >> 2) & 7);
            gl_lds16(Ah + (size_t)(m0 + r) * K + k0 + u * 8, Abuf + ch * 1024);
            gl_lds16(Bth + (size_t)(n0 + r) * K + k0 + u * 8, Bbuf + ch * 1024);
        }
    };

    char* A0 = smem;
    char* B0 = smem + 16384;
    char* A1 = smem + 32768;
    char* B1 = smem + 49152;

    stage(A0, B0, 0);
    __syncthreads();
    int nk = K / 64;
    for (int kt = 0; kt < nk; ++kt) {
        char* Ac = (kt & 1) ? A1 : A0;
        char* Bc = (kt & 1) ? B1 : B0;
        if (kt + 1 < nk)
            stage((kt & 1) ? A0 : A1, (kt & 1) ? B0 : B1, (kt + 1) * 64);
        __builtin_amdgcn_s_setprio(1);
        #pragma unroll
        for (int km = 0; km < 4; ++km) {
            int kk = km * 16 + hi * 8;
            bf16x8 ah[2], bh[2];
            ah[0] = *(bf16x8*)swzg(Ac, mh + ln31, kk);
            ah[1] = *(bf16x8*)swzg(Ac, mh + 32 + ln31, kk);
            bh[0] = *(bf16x8*)swzg(Bc, nh + ln31, kk);
            bh[1] = *(bf16x8*)swzg(Bc, nh + 32 + ln31, kk);
            #pragma unroll
            for (int mi = 0; mi < 2; ++mi)
                #pragma unroll
                for (int ni = 0; ni < 2; ++ni)
                    acc[mi][ni] = __builtin_amdgcn_mfma_f32_32x32x16_bf16(
                        ah[mi], bh[ni], acc[mi][ni], 0, 0, 0);
        }
        __builtin_amdgcn_s_setprio(0);
        __syncthreads();
    }
    float bv[2];
    bv[0] = bias[n0 + nh + ln31];
    bv[1] = bias[n0 + nh + 32 + ln31];
    #pragma unroll
    for (int mi = 0; mi < 2; ++mi)
        #pragma unroll
        for (int ni = 0; ni < 2; ++ni) {
            int n = n0 + nh + ni * 32 + ln31;
            #pragma unroll
            for (int r = 0; r < 16; ++r) {
                int m = m0 + mh + mi * 32 + (r & 3) + 8 * (r >> 2) + 4 * hi;
                float v = acc[mi][ni][r] + bv[ni];
                if (HASRES) v += resid[(size_t)m * N + n];
                if (RELU) v = fmaxf(v, 0.f);
                size_t idx = (size_t)m * N + n;
                if (OUT == 0) Cf[idx] = v;
                else Cbh[idx] = f2bf(v);
            }
        }
}

// ---------------------------------------------------------------------------
// Fused QKV GEMM (unchanged from round 5).
// ---------------------------------------------------------------------------
__global__ __launch_bounds__(256) void qkv_gemm(
        const ushort* __restrict__ Ah, const ushort* __restrict__ Al,
        const ushort* __restrict__ Bth, const ushort* __restrict__ Btl,
        const float* __restrict__ bq, const float* __restrict__ bk,
        const float* __restrict__ bv_, ushort* __restrict__ q_h,
        ushort* __restrict__ q_l, ushort* __restrict__ k_h,
        ushort* __restrict__ k_l, ushort* __restrict__ v_h) {
    const int K = DM, N = DM;
    __shared__ __align__(16) char smem[65536];
    char* As_h = smem;
    char* Bs_h = smem + 16384;
    char* As_l = smem + 32768;
    char* Bs_l = smem + 49152;
    int tid = threadIdx.x;
    int lane = tid & 63, w = tid >> 6;
    int ln31 = lane & 31, hi = lane >> 5;
    int mh = (w >> 1) * 64, nh = (w & 1) * 64;
    int gx = gridDim.x;  // 12
    int nwg = gx * gridDim.y;
    int flat = blockIdx.y * gx + blockIdx.x;
    int sid = (flat & 7) * (nwg >> 3) + (flat >> 3);
    int n0 = (sid % gx) * 128;
    int m0 = (sid / gx) * 128;
    bool isqk = (n0 < 1024);

    f32x16 acc[2][2];
    #pragma unroll
    for (int i = 0; i < 2; ++i)
        #pragma unroll
        for (int j = 0; j < 2; ++j)
            #pragma unroll
            for (int r = 0; r < 16; ++r) acc[i][j][r] = 0.f;

    for (int k0 = 0; k0 < K; k0 += 64) {
        #pragma unroll
        for (int c = 0; c < 4; ++c) {
            int ch = w * 4 + c;
            int r = ch * 8 + (lane >> 3);
            int u = (lane & 7) ^ ((r >> 2) & 7);
            gl_lds16(Ah + (size_t)(m0 + r) * K + k0 + u * 8, As_h + ch * 1024);
            gl_lds16(Bth + (size_t)(n0 + r) * K + k0 + u * 8, Bs_h + ch * 1024);
            if (isqk) {
                gl_lds16(Al + (size_t)(m0 + r) * K + k0 + u * 8, As_l + ch * 1024);
                gl_lds16(Btl + (size_t)(n0 + r) * K + k0 + u * 8, Bs_l + ch * 1024);
            }
        }
        __syncthreads();
        __builtin_amdgcn_s_setprio(1);
        #pragma unroll
        for (int km = 0; km < 4; ++km) {
            int kk = km * 16 + hi * 8;
            bf16x8 ah[2], bh[2];
            ah[0] = *(bf16x8*)swzg(As_h, mh + ln31, kk);
            ah[1] = *(bf16x8*)swzg(As_h, mh + 32 + ln31, kk);
            bh[0] = *(bf16x8*)swzg(Bs_h, nh + ln31, kk);
            bh[1] = *(bf16x8*)swzg(Bs_h, nh + 32 + ln31, kk);
            if (isqk) {
                bf16x8 al[2], bl[2];
                al[0] = *(bf16x8*)swzg(As_l, mh + ln31, kk);
                al[1] = *(bf16x8*)swzg(As_l, mh + 32 + ln31, kk);
                bl[0] = *(bf16x8*)swzg(Bs_l, nh + ln31, kk);
                bl[1] = *(bf16x8*)swzg(Bs_l, nh + 32 + ln31, kk);
                #pragma unroll
                for (int mi = 0; mi < 2; ++mi)
                    #pragma unroll
                    for (int ni = 0; ni < 2; ++ni) {
                        acc[mi][ni] = __builtin_amdgcn_mfma_f32_32x32x16_bf16(
                            ah[mi], bh[ni], acc[mi][ni], 0, 0, 0);
                        acc[mi][ni] = __builtin_amdgcn_mfma_f32_32x32x16_bf16(
                            ah[mi], bl[ni], acc[mi][ni], 0, 0, 0);
                        acc[mi][ni] = __builtin_amdgcn_mfma_f32_32x32x16_bf16(
                            al[mi], bh[ni], acc[mi][ni], 0, 0, 0);
                    }
            } else {
                #pragma unroll
                for (int mi = 0; mi < 2; ++mi)
                    #pragma unroll
                    for (int ni = 0; ni < 2; ++ni)
                        acc[mi][ni] = __builtin_amdgcn_mfma_f32_32x32x16_bf16(
                            ah[mi], bh[ni], acc[mi][ni], 0, 0, 0);
            }
        }
        __builtin_amdgcn_s_setprio(0);
        __syncthreads();
    }
    const float* bias = (n0 < 512) ? bq : (n0 < 1024 ? bk : bv_);
    int ncol0 = n0 & 511;
    ushort* Oh = (n0 < 512) ? q_h : (n0 < 1024 ? k_h : v_h);
    ushort* Ol = (n0 < 512) ? q_l : (n0 < 1024 ? k_l : nullptr);
    float bvv[2];
    bvv[0] = bias[ncol0 + nh + ln31];
    bvv[1] = bias[ncol0 + nh + 32 + ln31];
    #pragma unroll
    for (int mi = 0; mi < 2; ++mi)
        #pragma unroll
        for (int ni = 0; ni < 2; ++ni) {
            int n = ncol0 + nh + ni * 32 + ln31;
            #pragma unroll
            for (int r = 0; r < 16; ++r) {
                int m = m0 + mh + mi * 32 + (r & 3) + 8 * (r >> 2) + 4 * hi;
                float v = acc[mi][ni][r] + bvv[ni];
                size_t idx = (size_t)m * N + n;
                ushort hb = f2bf(v);
                Oh[idx] = hb;
                if (isqk) Ol[idx] = f2bf(v - bf2f(hb));
            }
        }
}

// ---------------------------------------------------------------------------
// MFMA flash attention. 48KB LDS (3 blocks/CU). P kept in registers and
// exchanged across the hi-halves with shfl_xor(32) — no P LDS round-trip.
// ---------------------------------------------------------------------------
__global__ __launch_bounds__(256, 3) void attn_kernel(
        const ushort* __restrict__ Qh, const ushort* __restrict__ Ql,
        const ushort* __restrict__ Khg, const ushort* __restrict__ Klg,
        const ushort* __restrict__ Vtg, const ushort* __restrict__ mb,
        ushort* __restrict__ O) {
    __shared__ __align__(16) char smem[49152];
    // buf0 @0, buf1 @24K; within buf: Kh +0, Kl +8K, Vt +16K
    int tid = threadIdx.x;
    int w = tid >> 6, lane = tid & 63;
    int ln31 = lane & 31, hi = lane >> 5;
    bool hib = (hi != 0);
    int f = blockIdx.y * gridDim.x + blockIdx.x;
    int g = (f & 7) * 64 + (f >> 3);
    int qb = g & 15, bh = g >> 4;
    int b = bh >> 3, h = bh & 7;
    int q0 = qb * 128;
    size_t brow = (size_t)b * SEQ;
    int hcol = h * DKH;

    auto stage_kv = [&](char* buf, int kt) {
        #pragma unroll
        for (int c = 0; c < 2; ++c) {
            int ch = w * 2 + c;
            int r = ch * 8 + (lane >> 3);
            int u = (lane & 7) ^ (r & 7);
            gl_lds16(Khg + (brow + kt * 64 + r) * DM + hcol + u * 8,
                     buf + ch * 1024);
            gl_lds16(Klg + (brow + kt * 64 + r) * DM + hcol + u * 8,
                     buf + 8192 + ch * 1024);
            gl_lds16(Vtg + ((size_t)bh * DKH + r) * SEQ + kt * 64 + u * 8,
                     buf + 16384 + ch * 1024);
        }
    };

    // prologue: stage Q (32KB over buf regions), read frags, then K/V tile 0
    {
        char* QhL = smem;
        char* QlL = smem + 16384;
        #pragma unroll
        for (int c = 0; c < 4; ++c) {
            int ch = w * 4 + c;
            int r = ch * 8 + (lane >> 3);
            int u = (lane & 7) ^ (r & 7);
            gl_lds16(Qh + (brow + q0 + r) * DM + hcol + u * 8, QhL + ch * 1024);
            gl_lds16(Ql + (brow + q0 + r) * DM + hcol + u * 8, QlL + ch * 1024);
        }
    }
    __syncthreads();
    bf16x8 qfh[4], qfl[4];
    {
        int qr = w * 32 + ln31;
        #pragma unroll
        for (int c = 0; c < 4; ++c) {
            qfh[c] = *(bf16x8*)swz(smem, qr, c * 16 + hi * 8);
            qfl[c] = *(bf16x8*)swz(smem + 16384, qr, c * 16 + hi * 8);
        }
    }
    __syncthreads();  // Q region reusable
    stage_kv(smem, 0);
    __syncthreads();  // drains the staging vmcnt

    f32x16 ctx0, ctx1;
    #pragma unroll
    for (int r = 0; r < 16; ++r) { ctx0[r] = 0.f; ctx1[r] = 0.f; }
    float m_i = -1e30f, l_i = 0.f;
    int qglob = q0 + w * 32 + ln31;
    const ushort* mrow = mb + (size_t)qglob * SEQ;

    for (int kt = 0; kt < SEQ / 64; ++kt) {
        char* cur = smem + (kt & 1) * 24576;
        if (kt + 1 < SEQ / 64)
            stage_kv(smem + ((kt + 1) & 1) * 24576, kt + 1);
        // prefetch this tile's mask values (8 x 8B, issued before MFMAs)
        ushort4 mpre[8];
        #pragma unroll
        for (int i = 0; i < 8; ++i)
            mpre[i] = *(const ushort4*)(mrow + kt * 64 + i * 8 + hi * 4);
        char* KhL = cur;
        char* KlL = cur + 8192;
        char* VtL = cur + 16384;
        #pragma unroll
        for (int ksub = 0; ksub < 2; ++ksub) {
            f32x16 s;
            #pragma unroll
            for (int r = 0; r < 16; ++r) s[r] = 0.f;
            __builtin_amdgcn_s_setprio(1);
            #pragma unroll
            for (int c = 0; c < 4; ++c) {
                bf16x8 ka = *(bf16x8*)swz(KhL, ksub * 32 + ln31, c * 16 + hi * 8);
                bf16x8 kb = *(bf16x8*)swz(KlL, ksub * 32 + ln31, c * 16 + hi * 8);
                s = __builtin_amdgcn_mfma_f32_32x32x16_bf16(ka, qfh[c], s, 0, 0, 0);
                s = __builtin_amdgcn_mfma_f32_32x32x16_bf16(ka, qfl[c], s, 0, 0, 0);
                s = __builtin_amdgcn_mfma_f32_32x32x16_bf16(kb, qfh[c], s, 0, 0, 0);
            }
            __builtin_amdgcn_s_setprio(0);
            float tmax = -1e30f;
            #pragma unroll
            for (int rg = 0; rg < 4; ++rg) {
                ushort4 mv = mpre[ksub * 4 + rg];
                ushort mu[4] = {mv.x, mv.y, mv.z, mv.w};
                #pragma unroll
                for (int j = 0; j < 4; ++j) {
                    int r = rg * 4 + j;
                    float sc = floorf(s[r] * 0.125f) + bf2f(mu[j]);
                    s[r] = sc;
                    tmax = fmaxf(tmax, sc);
                }
            }
            tmax = fmaxf(tmax, __shfl_xor(tmax, 32));
            if (!__all(tmax <= m_i)) {
                float newm = fmaxf(m_i, tmax);
                float scl = __expf(m_i - newm);
                m_i = newm;
                l_i *= scl;
                #pragma unroll
                for (int r = 0; r < 16; ++r) { ctx0[r] *= scl; ctx1[r] *= scl; }
            }
            float psum = 0.f;
            #pragma unroll
            for (int r = 0; r < 16; ++r) {
                float p = __expf(s[r] - m_i);
                s[r] = p;
                psum += p;
            }
            psum += __shfl_xor(psum, 32);
            l_i += psum;
            // pack P to bf16 pairs per rg, exchange across hi-halves in-reg
            uint pk0[4], pk1[4];
            #pragma unroll
            for (int rg = 0; rg < 4; ++rg) {
                pk0[rg] = cvtpk_bf16(s[rg * 4 + 0], s[rg * 4 + 1]);
                pk1[rg] = cvtpk_bf16(s[rg * 4 + 2], s[rg * 4 + 3]);
            }
            __builtin_amdgcn_s_setprio(1);
            #pragma unroll
            for (int cc = 0; cc < 2; ++cc) {
                uint A0 = pk0[cc * 2], A1 = pk1[cc * 2];         // rg = cc*2
                uint B0 = pk0[cc * 2 + 1], B1 = pk1[cc * 2 + 1]; // rg = cc*2+1
                uint send0 = hib ? A0 : B0;
                uint send1 = hib ? A1 : B1;
                uint own0  = hib ? B0 : A0;
                uint own1  = hib ? B1 : A1;
                uint recv0 = (uint)__shfl_xor((int)send0, 32);
                uint recv1 = (uint)__shfl_xor((int)send1, 32);
                union { uint u[4]; bf16x8 v; } pb;
                pb.u[0] = hib ? recv0 : own0;
                pb.u[1] = hib ? recv1 : own1;
                pb.u[2] = hib ? own0 : recv0;
                pb.u[3] = hib ? own1 : recv1;
                int c = ksub * 2 + cc;
                bf16x8 va0 = *(bf16x8*)swz(VtL, ln31, c * 16 + hi * 8);
                bf16x8 va1 = *(bf16x8*)swz(VtL, 32 + ln31, c * 16 + hi * 8);
                ctx0 = __builtin_amdgcn_mfma_f32_32x32x16_bf16(va0, pb.v, ctx0, 0, 0, 0);
                ctx1 = __builtin_amdgcn_mfma_f32_32x32x16_bf16(va1, pb.v, ctx1, 0, 0, 0);
            }
            __builtin_amdgcn_s_setprio(0);
        }
        __syncthreads();  // next tile staged; current fully consumed
    }

    float inv = 1.0f / l_i;
    ushort* op = O + (brow + qglob) * DM + hcol;
    #pragma unroll
    for (int r = 0; r < 16; ++r) {
        int d = (r & 3) + 8 * (r >> 2) + 4 * hi;
        op[d] = f2bf(ctx0[r] * inv);
        op[32 + d] = f2bf(ctx1[r] * inv);
    }
}

// ---------------------------------------------------------------------------
extern "C" void kernel_launch(void* const* d_in, const int* in_sizes, int n_in,
                              void* d_out, int out_size, void* d_ws, size_t ws_size,
                              hipStream_t stream) {
    const float* x    = (const float*)d_in[0];
    const int*   mask = (const int*)d_in[1];
    const float* wq = (const float*)d_in[2];
    const float* bq = (const float*)d_in[3];
    const float* wk = (const float*)d_in[4];
    const float* bk = (const float*)d_in[5];
    const float* wv = (const float*)d_in[6];
    const float* bv = (const float*)d_in[7];
    const float* wo = (const float*)d_in[8];
    const float* bo = (const float*)d_in[9];
    const float* w1 = (const float*)d_in[10];
    const float* b1 = (const float*)d_in[11];
    const float* w2 = (const float*)d_in[12];
    const float* b2 = (const float*)d_in[13];
    const float* g1  = (const float*)d_in[14];
    const float* be1 = (const float*)d_in[15];
    const float* g2  = (const float*)d_in[16];
    const float* be2 = (const float*)d_in[17];
    float* out = (float*)d_out;

    char* ws = (char*)d_ws;
    const size_t MiB = 1024 * 1024;
    ushort* xn_h = (ushort*)(ws);                 // 8 MiB
    ushort* xn_l = (ushort*)(ws + 8 * MiB);       // 8 MiB
    ushort* q_h  = (ushort*)(ws + 16 * MiB);      // 8 MiB
    ushort* q_l  = (ushort*)(ws + 24 * MiB);      // 8 MiB
    ushort* k_h  = (ushort*)(ws + 32 * MiB);      // 8 MiB
    ushort* k_l  = (ushort*)(ws + 40 * MiB);      // 8 MiB
    ushort* v_h  = (ushort*)(ws + 48 * MiB);      // 8 MiB
    ushort* v_t  = (ushort*)(ws + 56 * MiB);      // 8 MiB
    ushort* wqkvt_h = (ushort*)(ws + 64 * MiB);   // [1536][512] bf16, 1.5 MiB
    ushort* wqkvt_l = (ushort*)(ws + 66 * MiB);   // [1024][512] bf16, 1 MiB
    ushort* wot_h = (ushort*)(ws + 67 * MiB);     // 512 KiB
    ushort* w1t_h = (ushort*)(ws + 68 * MiB);     // 2 MiB
    ushort* w2t_h = (ushort*)(ws + 70 * MiB);     // 2 MiB
    ushort* mb    = (ushort*)(ws + 72 * MiB);     // 8 MiB
    // overlays
    ushort* ctx  = xn_h;                          // after qkv
    ushort* xn2  = xn_l;                          // after qkv
    ushort* ff1  = q_h;                           // 32 MiB over q,k (dead post-attn)

    dim3 blk256(256);
    wconv4<<<dim3(8, 8, 4), blk256, 0, stream>>>(
        wq, wk, wv, wo, wqkvt_h, wqkvt_l, wqkvt_h + 512 * 512,
        wqkvt_l + 512 * 512, wqkvt_h + 1024 * 512, wot_h);
    wconv<<<dim3(8, 32), blk256, 0, stream>>>(w1, w1t_h, DM, DFF);
    wconv<<<dim3(32, 8), blk256, 0, stream>>>(w2, w2t_h, DFF, DM);
    maskprep<<<SEQ * SEQ / 8 / 256, blk256, 0, stream>>>(mask, mb);
    ln_kernel<true><<<NROWS, 64, 0, stream>>>(x, g1, be1, xn_h, xn_l);
    qkv_gemm<<<dim3(12, NROWS / 128), blk256, 0, stream>>>(
        xn_h, xn_l, wqkvt_h, wqkvt_l, bq, bk, bv, q_h, q_l, k_h, k_l, v_h);
    vtrans<<<dim3(SEQ / 64, 4 * NH), blk256, 0, stream>>>(v_h, v_t);
    {
        dim3 grid(SEQ / 128, 4 * NH);
        attn_kernel<<<grid, blk256, 0, stream>>>(q_h, q_l, k_h, k_l, v_t, mb, ctx);
    }
    {
        dim3 grid(DM / 128, NROWS / 128);
        mgemm<false,true,0><<<grid, blk256, 0, stream>>>(
            ctx, wot_h, bo, x, out, nullptr, NROWS, DM, DM);
    }
    ln_kernel<false><<<NROWS, 64, 0, stream>>>(out, g2, be2, xn2, nullptr);
    {
        dim3 grid(DFF / 128, NROWS / 128);
        mgemm<true,false,1><<<grid, blk256, 0, stream>>>(
            xn2, w1t_h, b1, nullptr, nullptr, ff1, NROWS, DFF, DM);
    }
    {
        dim3 grid(DM / 128, NROWS / 128);
        mgemm<false,true,0><<<grid, blk256, 0, stream>>>(
            ff1, w2t_h, b2, out, out, nullptr, NROWS, DM, DFF);
    }
}

// Round 7
// 238.154 us; speedup vs baseline: 9.5643x; 1.0108x over previous
//
#include <hip/hip_runtime.h>
#include <cmath>

#define SEQ 2048
#define DM 512
#define DFF 2048
#define NH 8
#define DKH 64
#define NROWS 8192  // B*S = 4*2048

typedef __attribute__((ext_vector_type(8))) short bf16x8;
typedef __attribute__((ext_vector_type(16))) float f32x16;

__device__ __forceinline__ ushort f2bf(float f) {
    uint u = __float_as_uint(f);
    u += 0x7fff + ((u >> 16) & 1);
    return (ushort)(u >> 16);
}
__device__ __forceinline__ float bf2f(ushort h) {
    return __uint_as_float(((uint)h) << 16);
}
__device__ __forceinline__ uint cvtpk_bf16(float a, float b) {
    uint r;
    asm("v_cvt_pk_bf16_f32 %0, %1, %2" : "=v"(r) : "v"(a), "v"(b));
    return r;
}
// async global->LDS, 16B per lane. LDS dest = base + lane*16 (linear).
__device__ __forceinline__ void gl_lds16(const void* g, void* l) {
    __builtin_amdgcn_global_load_lds(
        (const __attribute__((address_space(1))) void*)g,
        (__attribute__((address_space(3))) void*)l, 16, 0, 0);
}
// 128B-row LDS swizzle (attn): byte ^= (row&7)<<4
__device__ __forceinline__ void* swz(char* base, int row, int col) {
    int byte = (row << 7) + (col << 1);
    byte ^= (row & 7) << 4;
    return base + byte;
}
// gemm LDS swizzle: byte ^= ((row>>2)&7)<<4
__device__ __forceinline__ void* swzg(char* base, int row, int k) {
    int byte = (row << 7) + (k << 1);
    byte ^= ((row >> 2) & 7) << 4;
    return base + byte;
}

// ---------------------------------------------------------------------------
// LayerNorm -> bf16 (hi, optional lo)
// ---------------------------------------------------------------------------
template<bool SPLIT>
__global__ __launch_bounds__(64) void ln_kernel(const float* __restrict__ x,
        const float* __restrict__ g, const float* __restrict__ b,
        ushort* __restrict__ oh, ushort* __restrict__ ol) {
    int row = blockIdx.x;
    int t = threadIdx.x;
    const float* xr = x + (size_t)row * DM + t * 8;
    float v[8];
    *(float4*)&v[0] = *(const float4*)(xr);
    *(float4*)&v[4] = *(const float4*)(xr + 4);
    float s = 0.f;
    #pragma unroll
    for (int j = 0; j < 8; ++j) s += v[j];
    #pragma unroll
    for (int m = 32; m > 0; m >>= 1) s += __shfl_xor(s, m);
    float mean = s * (1.0f / DM);
    float ss = 0.f;
    #pragma unroll
    for (int j = 0; j < 8; ++j) { float d = v[j] - mean; ss += d * d; }
    #pragma unroll
    for (int m = 32; m > 0; m >>= 1) ss += __shfl_xor(ss, m);
    float inv = 1.0f / (sqrtf(ss * (1.0f / (DM - 1))) + 1e-6f);
    float gv[8], bv[8];
    *(float4*)&gv[0] = *(const float4*)(g + t * 8);
    *(float4*)&gv[4] = *(const float4*)(g + t * 8 + 4);
    *(float4*)&bv[0] = *(const float4*)(b + t * 8);
    *(float4*)&bv[4] = *(const float4*)(b + t * 8 + 4);
    union { ushort us[8]; float4 f4; } ph, pl;
    #pragma unroll
    for (int j = 0; j < 8; ++j) {
        float o = gv[j] * (v[j] - mean) * inv + bv[j];
        ushort hb = f2bf(o);
        ph.us[j] = hb;
        if (SPLIT) pl.us[j] = f2bf(o - bf2f(hb));
    }
    *(float4*)(oh + (size_t)row * DM + t * 8) = ph.f4;
    if (SPLIT) *(float4*)(ol + (size_t)row * DM + t * 8) = pl.f4;
}

// ---------------------------------------------------------------------------
// Merged weight transpose+convert for the four 512x512 weights.
// ---------------------------------------------------------------------------
__global__ __launch_bounds__(256) void wconv4(
        const float* __restrict__ wq, const float* __restrict__ wk,
        const float* __restrict__ wv, const float* __restrict__ wo,
        ushort* __restrict__ qh, ushort* __restrict__ ql,
        ushort* __restrict__ kh, ushort* __restrict__ kl,
        ushort* __restrict__ vh, ushort* __restrict__ oh) {
    const int K = DM, N = DM;
    __shared__ float tile[64][65];
    int z = blockIdx.z;
    const float* W = (z == 0) ? wq : (z == 1) ? wk : (z == 2) ? wv : wo;
    ushort* Th = (z == 0) ? qh : (z == 1) ? kh : (z == 2) ? vh : oh;
    ushort* Tl = (z == 0) ? ql : (z == 1) ? kl : nullptr;
    bool split = (z < 2);
    int k0 = blockIdx.x * 64, n0 = blockIdx.y * 64;
    int t = threadIdx.x;
    {
        int kr = t >> 2, c0 = (t & 3) * 16;
        const float* src = W + (size_t)(k0 + kr) * N + n0 + c0;
        #pragma unroll
        for (int j = 0; j < 4; ++j)
            *(float4*)&tile[kr][c0 + j * 4] = *(const float4*)(src + j * 4);
    }
    __syncthreads();
    int n = t >> 2, kc = (t & 3) * 16;
    union { ushort us[16]; float4 f4[2]; } ph, pl;
    #pragma unroll
    for (int j = 0; j < 16; ++j) {
        float v = tile[kc + j][n];
        ushort hb = f2bf(v);
        ph.us[j] = hb;
        pl.us[j] = f2bf(v - bf2f(hb));
    }
    ushort* dh = Th + (size_t)(n0 + n) * K + k0 + kc;
    *(float4*)(dh) = ph.f4[0];
    *(float4*)(dh + 8) = ph.f4[1];
    if (split) {
        ushort* dl = Tl + (size_t)(n0 + n) * K + k0 + kc;
        *(float4*)(dl) = pl.f4[0];
        *(float4*)(dl + 8) = pl.f4[1];
    }
}

// ---------------------------------------------------------------------------
// Weight transpose+convert (single, for w1/w2)
// ---------------------------------------------------------------------------
__global__ __launch_bounds__(256) void wconv(const float* __restrict__ W,
        ushort* __restrict__ Th, int K, int N) {
    __shared__ float tile[64][65];
    int k0 = blockIdx.x * 64, n0 = blockIdx.y * 64;
    int t = threadIdx.x;
    {
        int kr = t >> 2, c0 = (t & 3) * 16;
        const float* src = W + (size_t)(k0 + kr) * N + n0 + c0;
        #pragma unroll
        for (int j = 0; j < 4; ++j)
            *(float4*)&tile[kr][c0 + j * 4] = *(const float4*)(src + j * 4);
    }
    __syncthreads();
    int n = t >> 2, kc = (t & 3) * 16;
    union { ushort us[16]; float4 f4[2]; } ph;
    #pragma unroll
    for (int j = 0; j < 16; ++j) ph.us[j] = f2bf(tile[kc + j][n]);
    ushort* dh = Th + (size_t)(n0 + n) * K + k0 + kc;
    *(float4*)(dh) = ph.f4[0];
    *(float4*)(dh + 8) = ph.f4[1];
}

// ---------------------------------------------------------------------------
// V transpose: vh[(b*SEQ+s)][DM] bf16 (head h cols) -> vt[(bh*64+d)][SEQ] bf16
// ---------------------------------------------------------------------------
__global__ __launch_bounds__(256) void vtrans(const ushort* __restrict__ vh,
        ushort* __restrict__ vt) {
    __shared__ __align__(16) char tile[8192];
    int s0 = blockIdx.x * 64;
    int bh = blockIdx.y;
    int b = bh >> 3, h = bh & 7;
    int t = threadIdx.x;
    {
        int r = t >> 2, co = (t & 3) * 16;
        const ushort* src = vh + (size_t)(b * SEQ + s0 + r) * DM + h * DKH + co;
        *(float4*)swz(tile, r, co) = *(const float4*)(src);
        *(float4*)swz(tile, r, co + 8) = *(const float4*)(src + 8);
    }
    __syncthreads();
    int d = t >> 2, j0 = (t & 3) * 16;
    union { ushort us[16]; float4 f4[2]; } o;
    #pragma unroll
    for (int j = 0; j < 16; ++j)
        o.us[j] = *(ushort*)swz(tile, j0 + j, d);
    ushort* dst = vt + ((size_t)bh * DKH + d) * SEQ + s0 + j0;
    *(float4*)(dst) = o.f4[0];
    *(float4*)(dst + 8) = o.f4[1];
}

// ---------------------------------------------------------------------------
// Mask -> additive bf16 bias {0,-1e9} + per-(row, 64-key-tile) all-ones flags.
// One 64-thread block per q-row.
// ---------------------------------------------------------------------------
__global__ __launch_bounds__(64) void maskprep(const int* __restrict__ mask,
        ushort* __restrict__ mb, unsigned char* __restrict__ mflag) {
    int row = blockIdx.x;
    int lane = threadIdx.x;
    ushort neg = f2bf(-1e9f);
    unsigned long long bal[4];
    #pragma unroll
    for (int u = 0; u < 4; ++u) {
        int base = row * SEQ + u * 512 + lane * 8;
        int4 a = *(const int4*)(mask + base);
        int4 c = *(const int4*)(mask + base + 4);
        union { ushort us[8]; float4 f4; } o;
        o.us[0] = a.x ? (ushort)0 : neg;
        o.us[1] = a.y ? (ushort)0 : neg;
        o.us[2] = a.z ? (ushort)0 : neg;
        o.us[3] = a.w ? (ushort)0 : neg;
        o.us[4] = c.x ? (ushort)0 : neg;
        o.us[5] = c.y ? (ushort)0 : neg;
        o.us[6] = c.z ? (ushort)0 : neg;
        o.us[7] = c.w ? (ushort)0 : neg;
        *(float4*)(mb + base) = o.f4;
        bool ok = a.x && a.y && a.z && a.w && c.x && c.y && c.z && c.w;
        bal[u] = __ballot(ok);
    }
    if (lane < 32) {
        int u = lane >> 3;
        unsigned long long bsel = bal[0];
        bsel = (u == 1) ? bal[1] : bsel;
        bsel = (u == 2) ? bal[2] : bsel;
        bsel = (u == 3) ? bal[3] : bsel;
        int byte = (int)((bsel >> ((lane & 7) * 8)) & 0xFFull);
        mflag[row * 32 + lane] = (byte == 0xFF) ? 1 : 0;
    }
}

// ---------------------------------------------------------------------------
// 1-term MFMA GEMM, double-buffered via global_load_lds prefetch.
// ---------------------------------------------------------------------------
template<bool RELU, bool HASRES, int OUT>
__global__ __launch_bounds__(256) void mgemm(
        const ushort* __restrict__ Ah, const ushort* __restrict__ Bth,
        const float* __restrict__ bias, const float* __restrict__ resid,
        float* __restrict__ Cf, ushort* __restrict__ Cbh,
        int M, int N, int K) {
    __shared__ __align__(16) char smem[65536];
    int tid = threadIdx.x;
    int lane = tid & 63, w = tid >> 6;
    int ln31 = lane & 31, hi = lane >> 5;
    int mh = (w >> 1) * 64, nh = (w & 1) * 64;
    int gx = gridDim.x;
    int nwg = gx * gridDim.y;
    int flat = blockIdx.y * gx + blockIdx.x;
    int sid = (flat & 7) * (nwg >> 3) + (flat >> 3);
    int n0 = (sid % gx) * 128;
    int m0 = (sid / gx) * 128;

    f32x16 acc[2][2];
    #pragma unroll
    for (int i = 0; i < 2; ++i)
        #pragma unroll
        for (int j = 0; j < 2; ++j)
            #pragma unroll
            for (int r = 0; r < 16; ++r) acc[i][j][r] = 0.f;

    auto stage = [&](char* Abuf, char* Bbuf, int k0) {
        #pragma unroll
        for (int c = 0; c < 4; ++c) {
            int ch = w * 4 + c;
            int r = ch * 8 + (lane >> 3);
            int u = (lane & 7) ^ ((r >> 2) & 7);
            gl_lds16(Ah + (size_t)(m0 + r) * K + k0 + u * 8, Abuf + ch * 1024);
            gl_lds16(Bth + (size_t)(n0 + r) * K + k0 + u * 8, Bbuf + ch * 1024);
        }
    };

    char* A0 = smem;
    char* B0 = smem + 16384;
    char* A1 = smem + 32768;
    char* B1 = smem + 49152;

    stage(A0, B0, 0);
    __syncthreads();
    int nk = K / 64;
    for (int kt = 0; kt < nk; ++kt) {
        char* Ac = (kt & 1) ? A1 : A0;
        char* Bc = (kt & 1) ? B1 : B0;
        if (kt + 1 < nk)
            stage((kt & 1) ? A0 : A1, (kt & 1) ? B0 : B1, (kt + 1) * 64);
        __builtin_amdgcn_s_setprio(1);
        #pragma unroll
        for (int km = 0; km < 4; ++km) {
            int kk = km * 16 + hi * 8;
            bf16x8 ah[2], bh[2];
            ah[0] = *(bf16x8*)swzg(Ac, mh + ln31, kk);
            ah[1] = *(bf16x8*)swzg(Ac, mh + 32 + ln31, kk);
            bh[0] = *(bf16x8*)swzg(Bc, nh + ln31, kk);
            bh[1] = *(bf16x8*)swzg(Bc, nh + 32 + ln31, kk);
            #pragma unroll
            for (int mi = 0; mi < 2; ++mi)
                #pragma unroll
                for (int ni = 0; ni < 2; ++ni)
                    acc[mi][ni] = __builtin_amdgcn_mfma_f32_32x32x16_bf16(
                        ah[mi], bh[ni], acc[mi][ni], 0, 0, 0);
        }
        __builtin_amdgcn_s_setprio(0);
        __syncthreads();
    }
    float bv[2];
    bv[0] = bias[n0 + nh + ln31];
    bv[1] = bias[n0 + nh + 32 + ln31];
    #pragma unroll
    for (int mi = 0; mi < 2; ++mi)
        #pragma unroll
        for (int ni = 0; ni < 2; ++ni) {
            int n = n0 + nh + ni * 32 + ln31;
            #pragma unroll
            for (int r = 0; r < 16; ++r) {
                int m = m0 + mh + mi * 32 + (r & 3) + 8 * (r >> 2) + 4 * hi;
                float v = acc[mi][ni][r] + bv[ni];
                if (HASRES) v += resid[(size_t)m * N + n];
                if (RELU) v = fmaxf(v, 0.f);
                size_t idx = (size_t)m * N + n;
                if (OUT == 0) Cf[idx] = v;
                else Cbh[idx] = f2bf(v);
            }
        }
}

// ---------------------------------------------------------------------------
// Fused QKV GEMM (unchanged).
// ---------------------------------------------------------------------------
__global__ __launch_bounds__(256) void qkv_gemm(
        const ushort* __restrict__ Ah, const ushort* __restrict__ Al,
        const ushort* __restrict__ Bth, const ushort* __restrict__ Btl,
        const float* __restrict__ bq, const float* __restrict__ bk,
        const float* __restrict__ bv_, ushort* __restrict__ q_h,
        ushort* __restrict__ q_l, ushort* __restrict__ k_h,
        ushort* __restrict__ k_l, ushort* __restrict__ v_h) {
    const int K = DM, N = DM;
    __shared__ __align__(16) char smem[65536];
    char* As_h = smem;
    char* Bs_h = smem + 16384;
    char* As_l = smem + 32768;
    char* Bs_l = smem + 49152;
    int tid = threadIdx.x;
    int lane = tid & 63, w = tid >> 6;
    int ln31 = lane & 31, hi = lane >> 5;
    int mh = (w >> 1) * 64, nh = (w & 1) * 64;
    int gx = gridDim.x;  // 12
    int nwg = gx * gridDim.y;
    int flat = blockIdx.y * gx + blockIdx.x;
    int sid = (flat & 7) * (nwg >> 3) + (flat >> 3);
    int n0 = (sid % gx) * 128;
    int m0 = (sid / gx) * 128;
    bool isqk = (n0 < 1024);

    f32x16 acc[2][2];
    #pragma unroll
    for (int i = 0; i < 2; ++i)
        #pragma unroll
        for (int j = 0; j < 2; ++j)
            #pragma unroll
            for (int r = 0; r < 16; ++r) acc[i][j][r] = 0.f;

    for (int k0 = 0; k0 < K; k0 += 64) {
        #pragma unroll
        for (int c = 0; c < 4; ++c) {
            int ch = w * 4 + c;
            int r = ch * 8 + (lane >> 3);
            int u = (lane & 7) ^ ((r >> 2) & 7);
            gl_lds16(Ah + (size_t)(m0 + r) * K + k0 + u * 8, As_h + ch * 1024);
            gl_lds16(Bth + (size_t)(n0 + r) * K + k0 + u * 8, Bs_h + ch * 1024);
            if (isqk) {
                gl_lds16(Al + (size_t)(m0 + r) * K + k0 + u * 8, As_l + ch * 1024);
                gl_lds16(Btl + (size_t)(n0 + r) * K + k0 + u * 8, Bs_l + ch * 1024);
            }
        }
        __syncthreads();
        __builtin_amdgcn_s_setprio(1);
        #pragma unroll
        for (int km = 0; km < 4; ++km) {
            int kk = km * 16 + hi * 8;
            bf16x8 ah[2], bh[2];
            ah[0] = *(bf16x8*)swzg(As_h, mh + ln31, kk);
            ah[1] = *(bf16x8*)swzg(As_h, mh + 32 + ln31, kk);
            bh[0] = *(bf16x8*)swzg(Bs_h, nh + ln31, kk);
            bh[1] = *(bf16x8*)swzg(Bs_h, nh + 32 + ln31, kk);
            if (isqk) {
                bf16x8 al[2], bl[2];
                al[0] = *(bf16x8*)swzg(As_l, mh + ln31, kk);
                al[1] = *(bf16x8*)swzg(As_l, mh + 32 + ln31, kk);
                bl[0] = *(bf16x8*)swzg(Bs_l, nh + ln31, kk);
                bl[1] = *(bf16x8*)swzg(Bs_l, nh + 32 + ln31, kk);
                #pragma unroll
                for (int mi = 0; mi < 2; ++mi)
                    #pragma unroll
                    for (int ni = 0; ni < 2; ++ni) {
                        acc[mi][ni] = __builtin_amdgcn_mfma_f32_32x32x16_bf16(
                            ah[mi], bh[ni], acc[mi][ni], 0, 0, 0);
                        acc[mi][ni] = __builtin_amdgcn_mfma_f32_32x32x16_bf16(
                            ah[mi], bl[ni], acc[mi][ni], 0, 0, 0);
                        acc[mi][ni] = __builtin_amdgcn_mfma_f32_32x32x16_bf16(
                            al[mi], bh[ni], acc[mi][ni], 0, 0, 0);
                    }
            } else {
                #pragma unroll
                for (int mi = 0; mi < 2; ++mi)
                    #pragma unroll
                    for (int ni = 0; ni < 2; ++ni)
                        acc[mi][ni] = __builtin_amdgcn_mfma_f32_32x32x16_bf16(
                            ah[mi], bh[ni], acc[mi][ni], 0, 0, 0);
            }
        }
        __builtin_amdgcn_s_setprio(0);
        __syncthreads();
    }
    const float* bias = (n0 < 512) ? bq : (n0 < 1024 ? bk : bv_);
    int ncol0 = n0 & 511;
    ushort* Oh = (n0 < 512) ? q_h : (n0 < 1024 ? k_h : v_h);
    ushort* Ol = (n0 < 512) ? q_l : (n0 < 1024 ? k_l : nullptr);
    float bvv[2];
    bvv[0] = bias[ncol0 + nh + ln31];
    bvv[1] = bias[ncol0 + nh + 32 + ln31];
    #pragma unroll
    for (int mi = 0; mi < 2; ++mi)
        #pragma unroll
        for (int ni = 0; ni < 2; ++ni) {
            int n = ncol0 + nh + ni * 32 + ln31;
            #pragma unroll
            for (int r = 0; r < 16; ++r) {
                int m = m0 + mh + mi * 32 + (r & 3) + 8 * (r >> 2) + 4 * hi;
                float v = acc[mi][ni][r] + bvv[ni];
                size_t idx = (size_t)m * N + n;
                ushort hb = f2bf(v);
                Oh[idx] = hb;
                if (isqk) Ol[idx] = f2bf(v - bf2f(hb));
            }
        }
}

// ---------------------------------------------------------------------------
// MFMA flash attention, split-K x2: each block handles 16 of 32 kt-tiles and
// writes unnormalized partial ctx (bf16) + (m,l). Grid 1024 blocks.
// ---------------------------------------------------------------------------
__global__ __launch_bounds__(256, 3) void attn_kernel(
        const ushort* __restrict__ Qh, const ushort* __restrict__ Ql,
        const ushort* __restrict__ Khg, const ushort* __restrict__ Klg,
        const ushort* __restrict__ Vtg, const ushort* __restrict__ mb,
        const unsigned char* __restrict__ mflag,
        ushort* __restrict__ pctx0, ushort* __restrict__ pctx1,
        float2* __restrict__ ml) {
    __shared__ __align__(16) char smem[49152];
    int tid = threadIdx.x;
    int w = tid >> 6, lane = tid & 63;
    int ln31 = lane & 31, hi = lane >> 5;
    bool hib = (hi != 0);
    // 1024 blocks; per XCD: 4 bh x (2 parts x 16 qb)
    int f = blockIdx.y * gridDim.x + blockIdx.x;
    int g = (f & 7) * 128 + (f >> 3);
    int bh = g >> 5, rest = g & 31;
    int part = rest >> 4, qb = rest & 15;
    int b = bh >> 3, h = bh & 7;
    int q0 = qb * 128;
    size_t brow = (size_t)b * SEQ;
    int hcol = h * DKH;
    int ktbeg = part * 16, ktend = ktbeg + 16;

    auto stage_kv = [&](char* buf, int kt) {
        #pragma unroll
        for (int c = 0; c < 2; ++c) {
            int ch = w * 2 + c;
            int r = ch * 8 + (lane >> 3);
            int u = (lane & 7) ^ (r & 7);
            gl_lds16(Khg + (brow + kt * 64 + r) * DM + hcol + u * 8,
                     buf + ch * 1024);
            gl_lds16(Klg + (brow + kt * 64 + r) * DM + hcol + u * 8,
                     buf + 8192 + ch * 1024);
            gl_lds16(Vtg + ((size_t)bh * DKH + r) * SEQ + kt * 64 + u * 8,
                     buf + 16384 + ch * 1024);
        }
    };

    // prologue: stage Q, read frags, then first K/V tile
    {
        char* QhL = smem;
        char* QlL = smem + 16384;
        #pragma unroll
        for (int c = 0; c < 4; ++c) {
            int ch = w * 4 + c;
            int r = ch * 8 + (lane >> 3);
            int u = (lane & 7) ^ (r & 7);
            gl_lds16(Qh + (brow + q0 + r) * DM + hcol + u * 8, QhL + ch * 1024);
            gl_lds16(Ql + (brow + q0 + r) * DM + hcol + u * 8, QlL + ch * 1024);
        }
    }
    __syncthreads();
    bf16x8 qfh[4], qfl[4];
    {
        int qr = w * 32 + ln31;
        #pragma unroll
        for (int c = 0; c < 4; ++c) {
            qfh[c] = *(bf16x8*)swz(smem, qr, c * 16 + hi * 8);
            qfl[c] = *(bf16x8*)swz(smem + 16384, qr, c * 16 + hi * 8);
        }
    }
    __syncthreads();
    stage_kv(smem + (ktbeg & 1) * 24576, ktbeg);
    __syncthreads();

    f32x16 ctx0, ctx1;
    #pragma unroll
    for (int r = 0; r < 16; ++r) { ctx0[r] = 0.f; ctx1[r] = 0.f; }
    float m_i = -1e30f, l_i = 0.f;
    int qglob = q0 + w * 32 + ln31;
    const ushort* mrow = mb + (size_t)qglob * SEQ;

    for (int kt = ktbeg; kt < ktend; ++kt) {
        char* cur = smem + (kt & 1) * 24576;
        if (kt + 1 < ktend)
            stage_kv(smem + ((kt + 1) & 1) * 24576, kt + 1);
        unsigned char fl = mflag[qglob * 32 + kt];
        bool domask = !__all(fl != 0);
        ushort4 mpre[8];
        if (domask) {
            #pragma unroll
            for (int i = 0; i < 8; ++i)
                mpre[i] = *(const ushort4*)(mrow + kt * 64 + i * 8 + hi * 4);
        }
        char* KhL = cur;
        char* KlL = cur + 8192;
        char* VtL = cur + 16384;
        #pragma unroll
        for (int ksub = 0; ksub < 2; ++ksub) {
            f32x16 s;
            #pragma unroll
            for (int r = 0; r < 16; ++r) s[r] = 0.f;
            __builtin_amdgcn_s_setprio(1);
            #pragma unroll
            for (int c = 0; c < 4; ++c) {
                bf16x8 ka = *(bf16x8*)swz(KhL, ksub * 32 + ln31, c * 16 + hi * 8);
                bf16x8 kb = *(bf16x8*)swz(KlL, ksub * 32 + ln31, c * 16 + hi * 8);
                s = __builtin_amdgcn_mfma_f32_32x32x16_bf16(ka, qfh[c], s, 0, 0, 0);
                s = __builtin_amdgcn_mfma_f32_32x32x16_bf16(ka, qfl[c], s, 0, 0, 0);
                s = __builtin_amdgcn_mfma_f32_32x32x16_bf16(kb, qfh[c], s, 0, 0, 0);
            }
            __builtin_amdgcn_s_setprio(0);
            float tmax = -1e30f;
            if (domask) {
                #pragma unroll
                for (int rg = 0; rg < 4; ++rg) {
                    ushort4 mv = mpre[ksub * 4 + rg];
                    ushort mu[4] = {mv.x, mv.y, mv.z, mv.w};
                    #pragma unroll
                    for (int j = 0; j < 4; ++j) {
                        int r = rg * 4 + j;
                        float sc = floorf(s[r] * 0.125f) + bf2f(mu[j]);
                        s[r] = sc;
                        tmax = fmaxf(tmax, sc);
                    }
                }
            } else {
                #pragma unroll
                for (int r = 0; r < 16; ++r) {
                    float sc = floorf(s[r] * 0.125f);
                    s[r] = sc;
                    tmax = fmaxf(tmax, sc);
                }
            }
            tmax = fmaxf(tmax, __shfl_xor(tmax, 32));
            if (!__all(tmax <= m_i)) {
                float newm = fmaxf(m_i, tmax);
                float scl = __expf(m_i - newm);
                m_i = newm;
                l_i *= scl;
                #pragma unroll
                for (int r = 0; r < 16; ++r) { ctx0[r] *= scl; ctx1[r] *= scl; }
            }
            float psum = 0.f;
            #pragma unroll
            for (int r = 0; r < 16; ++r) {
                float p = __expf(s[r] - m_i);
                s[r] = p;
                psum += p;
            }
            psum += __shfl_xor(psum, 32);
            l_i += psum;
            uint pk0[4], pk1[4];
            #pragma unroll
            for (int rg = 0; rg < 4; ++rg) {
                pk0[rg] = cvtpk_bf16(s[rg * 4 + 0], s[rg * 4 + 1]);
                pk1[rg] = cvtpk_bf16(s[rg * 4 + 2], s[rg * 4 + 3]);
            }
            __builtin_amdgcn_s_setprio(1);
            #pragma unroll
            for (int cc = 0; cc < 2; ++cc) {
                uint A0 = pk0[cc * 2], A1 = pk1[cc * 2];
                uint B0 = pk0[cc * 2 + 1], B1 = pk1[cc * 2 + 1];
                uint send0 = hib ? A0 : B0;
                uint send1 = hib ? A1 : B1;
                uint own0  = hib ? B0 : A0;
                uint own1  = hib ? B1 : A1;
                uint recv0 = (uint)__shfl_xor((int)send0, 32);
                uint recv1 = (uint)__shfl_xor((int)send1, 32);
                union { uint u[4]; bf16x8 v; } pb;
                pb.u[0] = hib ? recv0 : own0;
                pb.u[1] = hib ? recv1 : own1;
                pb.u[2] = hib ? own0 : recv0;
                pb.u[3] = hib ? own1 : recv1;
                int c = ksub * 2 + cc;
                bf16x8 va0 = *(bf16x8*)swz(VtL, ln31, c * 16 + hi * 8);
                bf16x8 va1 = *(bf16x8*)swz(VtL, 32 + ln31, c * 16 + hi * 8);
                ctx0 = __builtin_amdgcn_mfma_f32_32x32x16_bf16(va0, pb.v, ctx0, 0, 0, 0);
                ctx1 = __builtin_amdgcn_mfma_f32_32x32x16_bf16(va1, pb.v, ctx1, 0, 0, 0);
            }
            __builtin_amdgcn_s_setprio(0);
        }
        __syncthreads();
    }

    // epilogue: write unnormalized partial ctx (bf16) + (m,l)
    ushort* P = part ? pctx1 : pctx0;
    size_t pbase = ((size_t)bh * SEQ + qglob) * DKH;
    #pragma unroll
    for (int r = 0; r < 16; ++r) {
        int d = (r & 3) + 8 * (r >> 2) + 4 * hi;
        P[pbase + d] = f2bf(ctx0[r]);
        P[pbase + 32 + d] = f2bf(ctx1[r]);
    }
    if (hi == 0)
        ml[((size_t)part * 32 + bh) * SEQ + qglob] = make_float2(m_i, l_i);
}

// ---------------------------------------------------------------------------
// Combine the two split-K partials exactly; write ctx bf16 [b*SEQ+q][DM].
// ---------------------------------------------------------------------------
__global__ __launch_bounds__(256) void attn_combine(
        const ushort* __restrict__ p0, const ushort* __restrict__ p1,
        const float2* __restrict__ ml, ushort* __restrict__ O) {
    int idx = blockIdx.x * 256 + threadIdx.x;
    int d0 = (idx & 7) * 8;
    int q = (idx >> 3) & (SEQ - 1);
    int bh = idx >> 14;
    int b = bh >> 3, h = bh & 7;
    size_t pb = ((size_t)bh * SEQ + q) * DKH + d0;
    bf16x8 c0 = *(const bf16x8*)(p0 + pb);
    bf16x8 c1 = *(const bf16x8*)(p1 + pb);
    float2 e0 = ml[(size_t)bh * SEQ + q];
    float2 e1 = ml[((size_t)32 + bh) * SEQ + q];
    float m = fmaxf(e0.x, e1.x);
    float w0 = __expf(e0.x - m), w1 = __expf(e1.x - m);
    float inv = 1.0f / (e0.y * w0 + e1.y * w1);
    union { ushort us[8]; float4 f4; } o;
    #pragma unroll
    for (int j = 0; j < 8; ++j) {
        float v0 = bf2f((ushort)c0[j]);
        float v1 = bf2f((ushort)c1[j]);
        o.us[j] = f2bf((v0 * w0 + v1 * w1) * inv);
    }
    *(float4*)(O + ((size_t)(b * SEQ + q)) * DM + h * DKH + d0) = o.f4;
}

// ---------------------------------------------------------------------------
extern "C" void kernel_launch(void* const* d_in, const int* in_sizes, int n_in,
                              void* d_out, int out_size, void* d_ws, size_t ws_size,
                              hipStream_t stream) {
    const float* x    = (const float*)d_in[0];
    const int*   mask = (const int*)d_in[1];
    const float* wq = (const float*)d_in[2];
    const float* bq = (const float*)d_in[3];
    const float* wk = (const float*)d_in[4];
    const float* bk = (const float*)d_in[5];
    const float* wv = (const float*)d_in[6];
    const float* bv = (const float*)d_in[7];
    const float* wo = (const float*)d_in[8];
    const float* bo = (const float*)d_in[9];
    const float* w1 = (const float*)d_in[10];
    const float* b1 = (const float*)d_in[11];
    const float* w2 = (const float*)d_in[12];
    const float* b2 = (const float*)d_in[13];
    const float* g1  = (const float*)d_in[14];
    const float* be1 = (const float*)d_in[15];
    const float* g2  = (const float*)d_in[16];
    const float* be2 = (const float*)d_in[17];
    float* out = (float*)d_out;

    char* ws = (char*)d_ws;
    const size_t MiB = 1024 * 1024;
    ushort* xn_h = (ushort*)(ws);                 // 8 MiB
    ushort* xn_l = (ushort*)(ws + 8 * MiB);       // 8 MiB
    ushort* q_h  = (ushort*)(ws + 16 * MiB);      // 8 MiB
    ushort* q_l  = (ushort*)(ws + 24 * MiB);      // 8 MiB
    ushort* k_h  = (ushort*)(ws + 32 * MiB);      // 8 MiB
    ushort* k_l  = (ushort*)(ws + 40 * MiB);      // 8 MiB
    ushort* v_h  = (ushort*)(ws + 48 * MiB);      // 8 MiB
    ushort* v_t  = (ushort*)(ws + 56 * MiB);      // 8 MiB
    ushort* wqkvt_h = (ushort*)(ws + 64 * MiB);   // 1.5 MiB (dead after qkv)
    ushort* wqkvt_l = (ushort*)(ws + 66 * MiB);   // 1 MiB  (dead after qkv)
    ushort* wot_h = (ushort*)(ws + 67 * MiB);     // 512 KiB
    unsigned char* mflag = (unsigned char*)(ws + 67 * MiB + 512 * 1024); // 64 KiB
    ushort* w1t_h = (ushort*)(ws + 68 * MiB);     // 2 MiB
    ushort* w2t_h = (ushort*)(ws + 70 * MiB);     // 2 MiB
    ushort* mb    = (ushort*)(ws + 72 * MiB);     // 8 MiB
    ushort* pctx0 = (ushort*)(ws + 80 * MiB);     // 8 MiB
    ushort* pctx1 = (ushort*)(ws + 88 * MiB);     // 8 MiB
    float2* ml    = (float2*)(ws + 64 * MiB);     // 1 MiB, overlays wqkvt_h (dead)
    // overlays
    ushort* ctx  = xn_h;                          // after qkv
    ushort* xn2  = xn_l;                          // after qkv
    ushort* ff1  = q_h;                           // over q,k (dead post-attn)

    dim3 blk256(256);
    wconv4<<<dim3(8, 8, 4), blk256, 0, stream>>>(
        wq, wk, wv, wo, wqkvt_h, wqkvt_l, wqkvt_h + 512 * 512,
        wqkvt_l + 512 * 512, wqkvt_h + 1024 * 512, wot_h);
    wconv<<<dim3(8, 32), blk256, 0, stream>>>(w1, w1t_h, DM, DFF);
    wconv<<<dim3(32, 8), blk256, 0, stream>>>(w2, w2t_h, DFF, DM);
    maskprep<<<SEQ, 64, 0, stream>>>(mask, mb, mflag);
    ln_kernel<true><<<NROWS, 64, 0, stream>>>(x, g1, be1, xn_h, xn_l);
    qkv_gemm<<<dim3(12, NROWS / 128), blk256, 0, stream>>>(
        xn_h, xn_l, wqkvt_h, wqkvt_l, bq, bk, bv, q_h, q_l, k_h, k_l, v_h);
    vtrans<<<dim3(SEQ / 64, 4 * NH), blk256, 0, stream>>>(v_h, v_t);
    {
        dim3 grid(32, 32);  // 1024 blocks: 32 bh x (2 parts x 16 qb)
        attn_kernel<<<grid, blk256, 0, stream>>>(
            q_h, q_l, k_h, k_l, v_t, mb, mflag, pctx0, pctx1, ml);
    }
    attn_combine<<<32 * SEQ * 8 / 256, blk256, 0, stream>>>(pctx0, pctx1, ml, ctx);
    {
        dim3 grid(DM / 128, NROWS / 128);
        mgemm<false,true,0><<<grid, blk256, 0, stream>>>(
            ctx, wot_h, bo, x, out, nullptr, NROWS, DM, DM);
    }
    ln_kernel<false><<<NROWS, 64, 0, stream>>>(out, g2, be2, xn2, nullptr);
    {
        dim3 grid(DFF / 128, NROWS / 128);
        mgemm<true,false,1><<<grid, blk256, 0, stream>>>(
            xn2, w1t_h, b1, nullptr, nullptr, ff1, NROWS, DFF, DM);
    }
    {
        dim3 grid(DM / 128, NROWS / 128);
        mgemm<false,true,0><<<grid, blk256, 0, stream>>>(
            ff1, w2t_h, b2, out, out, nullptr, NROWS, DM, DFF);
    }
}